// Round 14
// baseline (478.638 us; speedup 1.0000x reference)
//
#include <hip/hip_runtime.h>
#include <math.h>

typedef __attribute__((ext_vector_type(4))) float f32x4;
typedef __attribute__((ext_vector_type(8))) short short8;   // 8 bf16 raw bits
typedef __attribute__((ext_vector_type(4))) short short4v;  // 4 bf16 raw bits

__device__ __forceinline__ float b2f(unsigned short u) {
  unsigned int x = ((unsigned int)u) << 16;
  return __builtin_bit_cast(float, x);
}
__device__ __forceinline__ unsigned short f2b(float f) {
  unsigned int x = __builtin_bit_cast(unsigned int, f);
  x += 0x7fffu + ((x >> 16) & 1u);   // round-to-nearest-even
  return (unsigned short)(x >> 16);
}

// async global->LDS, 16B per lane. LDS dest must be lane-contiguous (wave base + lane*16).
__device__ __forceinline__ void gload16(const unsigned short* g, unsigned short* l) {
  __builtin_amdgcn_global_load_lds(
      (__attribute__((address_space(1))) void*)(unsigned long long)(const void*)g,
      (__attribute__((address_space(3))) void*)l, 16, 0, 0);
}

#define BARR  { __builtin_amdgcn_sched_barrier(0); __builtin_amdgcn_s_barrier(); __builtin_amdgcn_sched_barrier(0); }
#define LBARR { __builtin_amdgcn_sched_barrier(0); asm volatile("s_waitcnt lgkmcnt(0)" ::: "memory"); __builtin_amdgcn_s_barrier(); __builtin_amdgcn_sched_barrier(0); }
// CROSS-WAVE RULE: vmcnt gate protecting a cooperatively-staged LDS buffer sits
// BEFORE the barrier preceding the reads. BUFFER RULE: a GEMM's C region must
// be disjoint from its A, B, and residual regions. REGISTER RULE (rounds 11/13
// lesson): unified VGPR/AGPR file — per-wave acc of 128 caps the CU at 2
// waves/SIMD; 64x64-per-wave tiles (acc=64) allow 4 waves/SIMD at ~116 regs.
#define VMW(n) { __builtin_amdgcn_sched_barrier(0); asm volatile("s_waitcnt vmcnt(" #n ")" ::: "memory"); __builtin_amdgcn_sched_barrier(0); }

// ---------------------------------------------------------------------------
// prep_kernel: x->bf16 + weight repacks + bias concat (unchanged, verified).
// ---------------------------------------------------------------------------
__global__ __launch_bounds__(256) void prep_kernel(
    const float* __restrict__ x, unsigned short* __restrict__ xb,
    const float* __restrict__ Wq, const float* __restrict__ Wk,
    const float* __restrict__ Wv, const float* __restrict__ Wo,
    const float* __restrict__ W1, const float* __restrict__ W2,
    const float* __restrict__ bq, const float* __restrict__ bk, const float* __restrict__ bv,
    const float* __restrict__ g1,
    unsigned short* __restrict__ BqkT, unsigned short* __restrict__ WoT,
    unsigned short* __restrict__ W1T, unsigned short* __restrict__ W2T,
    unsigned short* __restrict__ WvR,
    float* __restrict__ bqkv) {
  __shared__ float tile[64][65];
  int nb = blockIdx.x, t = threadIdx.x;
  if (nb < 16384) {
    long i = (long)nb * 256 + t;
    f32x4 a = ((const f32x4*)x)[i * 2];
    f32x4 b = ((const f32x4*)x)[i * 2 + 1];
    short8 o;
#pragma unroll
    for (int j = 0; j < 4; ++j) { o[j] = (short)f2b(a[j]); o[4 + j] = (short)f2b(b[j]); }
    ((short8*)xb)[i] = o;
    return;
  }
  int n0 = nb - 16384;
  if (n0 == 1088) {
#pragma unroll
    for (int it = 0; it < 12; ++it) {
      int idx = it * 256 + t;
      float v = (idx < 1024) ? bq[idx] : (idx < 2048 ? bk[idx - 1024] : bv[idx - 2048]);
      bqkv[idx] = v;
    }
    return;
  }
  if (n0 >= 832) {                        // WvR[d][h*64+e] = Wv[h][d][e] (copy+cvt)
    int rem = n0 - 832, h = rem >> 4, dc = rem & 15;
    int r = t >> 2, c0 = (t & 3) * 16;
    const float* s = Wv + ((long)h * 1024 + dc * 64 + r) * 64 + c0;
    unsigned short* d = WvR + (long)(dc * 64 + r) * 1024 + h * 64 + c0;
#pragma unroll
    for (int j4 = 0; j4 < 4; ++j4) {
      f32x4 v = *(const f32x4*)(s + j4 * 4);
      short4v o;
#pragma unroll
      for (int j = 0; j < 4; ++j) o[j] = (short)f2b(v[j]);
      *(short4v*)(d + j4 * 4) = o;
    }
    return;
  }
  const float* src; unsigned short* dst; int sld, dld;
  bool foldg = false; int dbase = 0;
  if (n0 < 512) {                         // Wq/Wk -> BqkT rows [w*1024 + h*64 + e]
    int w = n0 >> 8, rem = n0 & 255, h = rem >> 4, dc = rem & 15;
    const float* W = (w == 0) ? Wq : Wk;
    src = W + ((long)h * 1024 + dc * 64) * 64;                 sld = 64;
    dst = BqkT + (long)(w * 1024 + h * 64) * 1024 + dc * 64;   dld = 1024;
  } else if (n0 < 768) {
    int rem = n0 - 512, dr = rem >> 4, jc = rem & 15;
    src = Wo + (long)dr * 64 * 1024 + jc * 64;                 sld = 1024;
    dst = WoT + (long)jc * 64 * 1024 + dr * 64;                dld = 1024;
  } else if (n0 < 800) {
    int rem = n0 - 768, dr = rem >> 1, fc = rem & 1;
    src = W1 + (long)dr * 64 * 128 + fc * 64;                  sld = 128;
    dst = W1T + (long)fc * 64 * 1024 + dr * 64;                dld = 1024;
    foldg = true; dbase = dr * 64;
  } else {
    int rem = n0 - 800, fr = rem >> 4, jc = rem & 15;
    src = W2 + (long)fr * 64 * 1024 + jc * 64;                 sld = 1024;
    dst = W2T + (long)jc * 64 * 128 + fr * 64;                 dld = 128;
  }
  int r = t >> 2, c0 = (t & 3) * 16;
#pragma unroll
  for (int j4 = 0; j4 < 4; ++j4) {
    f32x4 v = *(const f32x4*)(src + (long)r * sld + c0 + j4 * 4);
    tile[c0 + j4 * 4 + 0][r] = v[0];
    tile[c0 + j4 * 4 + 1][r] = v[1];
    tile[c0 + j4 * 4 + 2][r] = v[2];
    tile[c0 + j4 * 4 + 3][r] = v[3];
  }
  __syncthreads();
  short8 o0, o1;
#pragma unroll
  for (int j = 0; j < 8; ++j) {
    float v0 = tile[r][c0 + j], v1 = tile[r][c0 + 8 + j];
    if (foldg) { v0 *= g1[dbase + c0 + j]; v1 *= g1[dbase + c0 + 8 + j]; }
    o0[j] = (short)f2b(v0);
    o1[j] = (short)f2b(v1);
  }
  *(short8*)(dst + (long)r * dld + c0) = o0;
  *(short8*)(dst + (long)r * dld + c0 + 8) = o1;
}

// ---------------------------------------------------------------------------
// 256x256 bf16 GEMM v4 "16-wave": 16 waves (4M x 4N), 1024 threads, per-wave
// 64x64 output (acc = 64 regs -> 4 waves/SIMD at ~116 unified regs). BK=32,
// LDS 64KB = 2 bufs x 32KB; each buf = 256 rows x 128B, row r = A[r] 64B
// (logical slots 0-3) | B[r] 64B (slots 4-7), physical slot = logical^(r&7)
// (same proven 0-conflict swizzle family as v2.3). Per tile: rd 8 frags +
// 16 MFMA; LBARR; stage t+2; VMW(2) before BARR (cross-wave rule).
// EPI: 0 = +bias ; 5 = +bias + h1*rs*g1 resid ; 6 = no bias ;
//      7 = +bias(per-batch) + bias2 + bf16 resid + row-SS atomics.
// BSEL: per-batch B. BBIAS: per-batch bias. M%256==0, N%256==0, K%64==0.
// ---------------------------------------------------------------------------
template <int EPI, int BSEL, int BBIAS>
__global__ __launch_bounds__(1024, 4) void gemm16w(
    const unsigned short* __restrict__ A, int lda,
    const unsigned short* __restrict__ Bt, int ldb,
    unsigned short* __restrict__ C, int ldc,
    const float* __restrict__ bias,
    const unsigned short* __restrict__ residb, int ldr,
    float* __restrict__ ssb, const float* __restrict__ aux,
    int K, int NBX) {
  extern __shared__ char smb[];
  const int tid = threadIdx.x;
  const int lane = tid & 63, wid = tid >> 6;     // wid 0..15
  const int wm = wid >> 2, wn = wid & 3;         // 4M x 4N

  // XCD chunking (verified): mpx m-blocks per XCD, inner 4xNBX tile.
  int orig = blockIdx.x;
  int xcd = orig & 7, j = orig >> 3;
  int perx = gridDim.x >> 3;
  int mpx = perx / NBX;
  int ms = j / (4 * NBX), nb = (j >> 2) % NBX, mq = j & 3;
  const long m0 = (long)(xcd * mpx + ms * 4 + mq) * 256;
  const long n0 = (long)nb * 256;
  const unsigned short* bt = BSEL ? (Bt + (m0 >> 12) * 1048576) : Bt;
  const float* biasp = BBIAS ? (bias + (m0 >> 12) * 1024) : bias;

  const int NT = K >> 5;   // BK=32

  const int lr = lane & 15, lg = lane >> 4;
  const char* pA = smb + wm * 8192 + lr * 128 + ((lg ^ (lr & 7)) << 4);
  const char* pB = smb + wn * 8192 + lr * 128 + (((4 + lg) ^ (lr & 7)) << 4);

  f32x4 acc[4][4] = {};

  // stage half (rows half*128..+128) of the combined A|B tile kt into buf.
  auto stage = [&](int buf, int half, int kt) {
    int o = half * 16384 + tid * 16;
    int r = o >> 7, sl = (o >> 4) & 7;
    int v = sl ^ (r & 7);                 // logical slot stored at this phys slot
    const unsigned short* src = (v < 4)
        ? A + (m0 + r) * (long)lda + kt * 32 + v * 8
        : bt + (n0 + r) * (long)ldb + kt * 32 + (v - 4) * 8;
    gload16(src, (unsigned short*)(smb + buf + o));
  };

  // Prologue: stage tiles 0 (buf0) and 1 (buf1); gate tile 0 BEFORE barrier.
  stage(0, 0, 0); stage(0, 1, 0);
  stage(32768, 0, 1); stage(32768, 1, 1);
  VMW(2);     // oldest 2 = tile 0's loads landed (every wave, pre-barrier)
  BARR;

  for (int t = 0; t < NT; ++t) {
    int buf = (t & 1) << 15;
    short8 afr[4], bfr[4];
#pragma unroll
    for (int f = 0; f < 4; ++f) afr[f] = *(const short8*)(pA + buf + f * 2048);
#pragma unroll
    for (int g = 0; g < 4; ++g) bfr[g] = *(const short8*)(pB + buf + g * 2048);
    __builtin_amdgcn_s_setprio(1);
#pragma unroll
    for (int f = 0; f < 4; ++f)
#pragma unroll
      for (int g = 0; g < 4; ++g)
        acc[f][g] = __builtin_amdgcn_mfma_f32_16x16x32_bf16(afr[f], bfr[g], acc[f][g], 0, 0, 0);
    __builtin_amdgcn_s_setprio(0);
    LBARR;                         // all waves' reads of buf drained
    if (t + 2 < NT) {
      stage(buf, 0, t + 2);        // overwrite buf (safe: reads drained)
      stage(buf, 1, t + 2);
      VMW(2);                      // tile t+1's stages landed, before barrier
    } else {
      VMW(0);
    }
    BARR;                          // next tile may read buf^1
  }

  // Epilogue. EPI7 accumulates per-row sum-of-squares into ssb.
#pragma unroll
  for (int f = 0; f < 4; ++f) {
    float ssp[4] = {0.0f, 0.0f, 0.0f, 0.0f};
#pragma unroll
    for (int g = 0; g < 4; ++g) {
      long col = n0 + wn * 64 + g * 16 + (lane & 15);
      float bv = (EPI == 6) ? 0.0f : biasp[col];
      if (EPI == 7) bv += aux[col];              // aux = bo
      float gv = (EPI == 5) ? aux[col] : 0.0f;   // aux = g1
#pragma unroll
      for (int r = 0; r < 4; ++r) {
        long row = m0 + wm * 64 + f * 16 + (lane >> 4) * 4 + r;
        float o = acc[f][g][r] + bv;
        if (EPI == 7) o += b2f(residb[row * (long)ldr + col]);
        if (EPI == 5) {
          float rsv = rsqrtf(ssb[row] * (1.0f / 1024.0f) + 1e-6f);
          o += b2f(residb[row * (long)ldr + col]) * rsv * gv;
        }
        if (EPI == 7) ssp[r] += o * o;
        C[row * (long)ldc + col] = f2b(o);
      }
    }
    if (EPI == 7) {
#pragma unroll
      for (int r = 0; r < 4; ++r) {
        float p = ssp[r];
        p += __shfl_xor(p, 1, 64);
        p += __shfl_xor(p, 2, 64);
        p += __shfl_xor(p, 4, 64);
        p += __shfl_xor(p, 8, 64);
        if ((lane & 15) == 0) {
          long row = m0 + wm * 64 + f * 16 + (lane >> 4) * 4 + r;
          atomicAdd(&ssb[row], p);
        }
      }
    }
  }
}

// ---------------------------------------------------------------------------
// m97-structure GEMM for FF1 (N=128). EPI 4: o = tanh(rs(ssb[row])*acc + bias).
// ---------------------------------------------------------------------------
template <int EPI>
__global__ __launch_bounds__(256, 2) void gemm_bt(
    const unsigned short* __restrict__ A, int lda,
    const unsigned short* __restrict__ Bt, int ldb,
    unsigned short* __restrict__ C, int ldc,
    const float* __restrict__ bias, const float* __restrict__ ssb, int K) {
  __shared__ __align__(16) unsigned short Asm[128 * 32];
  __shared__ __align__(16) unsigned short Bsm[128 * 32];
  const int tid = threadIdx.x;
  const int lane = tid & 63, wid = tid >> 6;
  const int wr = wid >> 1, wc = wid & 1;
  const long m0 = (long)blockIdx.y * 128;
  const long n0 = (long)blockIdx.x * 128;

  f32x4 acc[4][4] = {};

  for (int kk = 0; kk < K; kk += 32) {
    __syncthreads();
#pragma unroll
    for (int i = 0; i < 2; ++i) {
      int slot = i * 256 + tid;
      int r = slot >> 2, cg = (slot & 3) * 8;
      gload16(A + (m0 + r) * (long)lda + kk + cg, &Asm[slot * 8]);
      gload16(Bt + (n0 + r) * (long)ldb + kk + cg, &Bsm[slot * 8]);
    }
    __syncthreads();
    short8 af[4], bfr[4];
#pragma unroll
    for (int mt = 0; mt < 4; ++mt)
      af[mt] = *(const short8*)&Asm[(wr * 64 + mt * 16 + (lane & 15)) * 32 + (lane >> 4) * 8];
#pragma unroll
    for (int nt = 0; nt < 4; ++nt)
      bfr[nt] = *(const short8*)&Bsm[(wc * 64 + nt * 16 + (lane & 15)) * 32 + (lane >> 4) * 8];
#pragma unroll
    for (int mt = 0; mt < 4; ++mt)
#pragma unroll
      for (int nt = 0; nt < 4; ++nt)
        acc[mt][nt] = __builtin_amdgcn_mfma_f32_16x16x32_bf16(af[mt], bfr[nt], acc[mt][nt], 0, 0, 0);
  }

  const long row0 = m0 + wr * 64 + ((lane >> 4) * 4);
  const long col0 = n0 + wc * 64 + (lane & 15);
#pragma unroll
  for (int mt = 0; mt < 4; ++mt) {
#pragma unroll
    for (int nt = 0; nt < 4; ++nt) {
      long col = col0 + nt * 16;
      float bv = bias[col];
      f32x4 v = acc[mt][nt];
#pragma unroll
      for (int r = 0; r < 4; ++r) {
        long row = row0 + mt * 16 + r;
        float o = v[r];
        if (EPI == 4) {
          float rsv = rsqrtf(ssb[row] * (1.0f / 1024.0f) + 1e-6f);
          o = tanhf(o * rsv + bv);
        } else o += bv;
        C[row * (long)ldc + col] = f2b(o);
      }
    }
  }
}

// ---------------------------------------------------------------------------
// scores via MFMA (verified rounds 5-13); QK buffer stride 2048.
// ---------------------------------------------------------------------------
__device__ __forceinline__ int sperm(int e) { return ((e + (e >> 3)) & 7) << 4; }

__global__ __launch_bounds__(256) void scores_mfma(
    const unsigned short* __restrict__ QK, float* __restrict__ part) {
  __shared__ __align__(16) char lds[32768];
  int bh = blockIdx.x, seg = blockIdx.y;
  int b = bh >> 4, h = bh & 15;
  int tid = threadIdx.x, lane = tid & 63, wid = tid >> 6;
  int e0 = (tid & 7) * 8;
  int sl0 = (tid >> 3) * 4;
  const unsigned short* Qg = QK + h * 64;
  const unsigned short* Kg = QK + 1024 + h * 64;
  f32x4 acc[4] = {};

  for (int ch = 0; ch < 8; ++ch) {
    long S0 = (long)b * 4096 + seg * 1024 + ch * 128;
    __syncthreads();
    short8 kv0 = *(const short8*)(Kg + (S0 + sl0 + 0) * 2048 + e0);
    short8 kv1 = *(const short8*)(Kg + (S0 + sl0 + 1) * 2048 + e0);
    short8 kv2 = *(const short8*)(Kg + (S0 + sl0 + 2) * 2048 + e0);
    short8 kv3 = *(const short8*)(Kg + (S0 + sl0 + 3) * 2048 + e0);
    short8 qv0 = *(const short8*)(Qg + (S0 + sl0 + 0) * 2048 + e0);
    short8 qv1 = *(const short8*)(Qg + (S0 + sl0 + 1) * 2048 + e0);
    short8 qv2 = *(const short8*)(Qg + (S0 + sl0 + 2) * 2048 + e0);
    short8 qv3 = *(const short8*)(Qg + (S0 + sl0 + 3) * 2048 + e0);
#pragma unroll
    for (int je = 0; je < 8; ++je) {
      int e = e0 + je;
      int sw = sperm(e);
      char* rowK = lds + e * 256;
      char* rowQ = lds + 16384 + e * 256;
      unsigned int klo = (unsigned short)kv0[je] | ((unsigned int)(unsigned short)kv1[je] << 16);
      unsigned int khi = (unsigned short)kv2[je] | ((unsigned int)(unsigned short)kv3[je] << 16);
      unsigned int qlo = (unsigned short)qv0[je] | ((unsigned int)(unsigned short)qv1[je] << 16);
      unsigned int qhi = (unsigned short)qv2[je] | ((unsigned int)(unsigned short)qv3[je] << 16);
      *(unsigned int*)(rowK + ((sl0 * 2) ^ sw)) = klo;
      *(unsigned int*)(rowK + ((sl0 * 2 + 4) ^ sw)) = khi;
      *(unsigned int*)(rowQ + ((sl0 * 2) ^ sw)) = qlo;
      *(unsigned int*)(rowQ + ((sl0 * 2 + 4) ^ sw)) = qhi;
    }
    __syncthreads();
#pragma unroll
    for (int ksi = 0; ksi < 4; ++ksi) {
      int colb = ksi * 64 + (lane >> 4) * 16;
      int erA = wid * 16 + (lane & 15);
      short8 af = *(const short8*)(lds + erA * 256 + (colb ^ sperm(erA)));
#pragma unroll
      for (int n = 0; n < 4; ++n) {
        int erB = n * 16 + (lane & 15);
        short8 bf = *(const short8*)(lds + 16384 + erB * 256 + (colb ^ sperm(erB)));
        acc[n] = __builtin_amdgcn_mfma_f32_16x16x32_bf16(af, bf, acc[n], 0, 0, 0);
      }
    }
  }
  float* dst = part + ((long)bh * 4 + seg) * 4096;
#pragma unroll
  for (int n = 0; n < 4; ++n)
#pragma unroll
    for (int r = 0; r < 4; ++r) {
      int k = wid * 16 + (lane >> 4) * 4 + r;
      int q = n * 16 + (lane & 15);
      dst[k * 64 + q] = acc[n][r];
    }
}

// softmax over k (per q column), scores/8; writes w row-major: Wb[bh][k][q]
__global__ __launch_bounds__(64) void softmax_Wb(
    const float* __restrict__ part, const int* __restrict__ mask,
    unsigned short* __restrict__ Wb) {
  __shared__ float lt[64][65];
  int bh = blockIdx.x, q = threadIdx.x;
  int b = bh >> 4;
  const float* p0 = part + (long)bh * 4 * 4096;
  float s[64];
#pragma unroll
  for (int k = 0; k < 64; ++k)
    s[k] = p0[k * 64 + q] + p0[4096 + k * 64 + q] + p0[8192 + k * 64 + q] + p0[12288 + k * 64 + q];
  bool live = (mask[b * 64 + q] != 0);
  float m = -1e30f;
#pragma unroll
  for (int k = 0; k < 64; ++k) m = fmaxf(m, s[k]);
  float sum = 0.0f;
#pragma unroll
  for (int k = 0; k < 64; ++k) {
    s[k] = __expf((s[k] - m) * 0.125f);
    sum += s[k];
  }
  float inv = live ? 1.0f / sum : 0.0f;
#pragma unroll
  for (int k = 0; k < 64; ++k) lt[k][q] = s[k] * inv;
  __syncthreads();
  unsigned short* o = Wb + (long)bh * 4096 + q * 64;
#pragma unroll
  for (int j8 = 0; j8 < 8; ++j8) {
    short8 ov;
#pragma unroll
    for (int j = 0; j < 8; ++j) ov[j] = (short)f2b(lt[q][j8 * 8 + j]);
    *(short8*)(o + j8 * 8) = ov;
  }
}

// WPT[b][d][h*64+k] = sum_q Wo[h*64+q][d] * w_bh[k][q]
// Fused: atomicAdd partial of hb[b][d] = sum_col WPT[d][col]*bv[col].
__global__ __launch_bounds__(256) void wpt_kernel(
    const unsigned short* __restrict__ WoT, const unsigned short* __restrict__ Wb,
    unsigned short* __restrict__ WPT, const float* __restrict__ bv,
    float* __restrict__ hb) {
  int dblk = blockIdx.x;   // 4
  int h = blockIdx.y;      // 16
  int b = blockIdx.z;      // 8
  int tid = threadIdx.x, lane = tid & 63, wid = tid >> 6;
  int d0 = dblk * 256 + wid * 64;
  const unsigned short* wb = Wb + (long)(b * 16 + h) * 4096;
  f32x4 acc[4][4] = {};
#pragma unroll
  for (int ks = 0; ks < 2; ++ks) {
    short8 bf[4];
#pragma unroll
    for (int nt = 0; nt < 4; ++nt)
      bf[nt] = *(const short8*)(wb + (nt * 16 + (lane & 15)) * 64 + ks * 32 + (lane >> 4) * 8);
#pragma unroll
    for (int mt = 0; mt < 4; ++mt) {
      short8 af = *(const short8*)(WoT + (long)(d0 + mt * 16 + (lane & 15)) * 1024 + h * 64 + ks * 32 + (lane >> 4) * 8);
#pragma unroll
      for (int nt = 0; nt < 4; ++nt)
        acc[mt][nt] = __builtin_amdgcn_mfma_f32_16x16x32_bf16(af, bf[nt], acc[mt][nt], 0, 0, 0);
    }
  }
  float bvv[4];
#pragma unroll
  for (int nt = 0; nt < 4; ++nt) bvv[nt] = bv[h * 64 + nt * 16 + (lane & 15)];
#pragma unroll
  for (int mt = 0; mt < 4; ++mt) {
#pragma unroll
    for (int r = 0; r < 4; ++r) {
      long row = d0 + mt * 16 + (lane >> 4) * 4 + r;
      float p = 0.0f;
#pragma unroll
      for (int nt = 0; nt < 4; ++nt) {
        float o = acc[mt][nt][r];
        WPT[(long)b * 1048576 + row * 1024 + h * 64 + nt * 16 + (lane & 15)] = f2b(o);
        p += o * bvv[nt];
      }
      p += __shfl_xor(p, 1, 64);
      p += __shfl_xor(p, 2, 64);
      p += __shfl_xor(p, 4, 64);
      p += __shfl_xor(p, 8, 64);
      if ((lane & 15) == 0) atomicAdd(&hb[b * 1024 + row], p);
    }
  }
}

// rmsnorm over D=1024; one block per row. bf16 in; f32 out.
__global__ __launch_bounds__(256) void rmsnorm_k(
    const unsigned short* __restrict__ in, const float* __restrict__ g,
    float* __restrict__ outf) {
  long row = blockIdx.x;
  int tid = threadIdx.x;
  short4v u = *(const short4v*)(in + row * 1024 + tid * 4);
  float v[4];
  float ss = 0.0f;
#pragma unroll
  for (int i = 0; i < 4; ++i) {
    v[i] = b2f((unsigned short)u[i]);
    ss += v[i] * v[i];
  }
#pragma unroll
  for (int off = 32; off > 0; off >>= 1) ss += __shfl_xor(ss, off, 64);
  __shared__ float wsum[4];
  if ((tid & 63) == 0) wsum[tid >> 6] = ss;
  __syncthreads();
  float tot = wsum[0] + wsum[1] + wsum[2] + wsum[3];
  float rsv = rsqrtf(tot * (1.0f / 1024.0f) + 1e-6f);
  f32x4 gv = *(const f32x4*)(g + tid * 4);
  f32x4 ov;
#pragma unroll
  for (int i = 0; i < 4; ++i) ov[i] = v[i] * rsv * gv[i];
  *(f32x4*)(outf + row * 1024 + tid * 4) = ov;
}

// ---------------------------------------------------------------------------
extern "C" void kernel_launch(void* const* d_in, const int* in_sizes, int n_in,
                              void* d_out, int out_size, void* d_ws, size_t ws_size,
                              hipStream_t stream) {
  const float* x  = (const float*)d_in[0];
  const int* mask = (const int*)d_in[1];
  const float* Wq = (const float*)d_in[2];
  const float* bq = (const float*)d_in[3];
  const float* Wk = (const float*)d_in[4];
  const float* bk = (const float*)d_in[5];
  const float* Wv = (const float*)d_in[6];
  const float* bv = (const float*)d_in[7];
  const float* Wo = (const float*)d_in[8];
  const float* bo = (const float*)d_in[9];
  const float* W1 = (const float*)d_in[10];
  const float* b1 = (const float*)d_in[11];
  const float* W2 = (const float*)d_in[12];
  const float* b2 = (const float*)d_in[13];
  const float* g1 = (const float*)d_in[14];
  const float* g2 = (const float*)d_in[15];

  char* ws = (char*)d_ws;
  size_t off = 0;
  auto alc = [&](size_t n) { size_t o = off; off += (n + 255) & ~(size_t)255; return o; };
  unsigned short* BqkT  = (unsigned short*)(ws + alc(2048UL * 1024 * 2));
  unsigned short* WoT   = (unsigned short*)(ws + alc(1024UL * 1024 * 2));
  unsigned short* W1T   = (unsigned short*)(ws + alc(128UL * 1024 * 2));    // g1-folded
  unsigned short* W2T   = (unsigned short*)(ws + alc(1024UL * 128 * 2));
  unsigned short* WvR   = (unsigned short*)(ws + alc(1024UL * 1024 * 2));
  float*          bqkv  = (float*)(ws + alc(3072UL * 4));
  float*          HBb   = (float*)(ws + alc(8192UL * 4));
  unsigned short* R0    = (unsigned short*)(ws + alc(32768UL * 1024 * 2));  // xb -> hf
  unsigned short* R1    = (unsigned short*)(ws + alc(32768UL * 2048 * 2));  // QK
  unsigned short* R2    = (unsigned short*)(ws + alc(32768UL * 1024 * 2));  // h1
  unsigned short* WPb   = (unsigned short*)(ws + alc(8UL * 1048576 * 2));   // WPT
  unsigned short* WVPb  = (unsigned short*)(ws + alc(8UL * 1048576 * 2));   // WVP
  unsigned short* Tb    = (unsigned short*)(ws + alc(32768UL * 128 * 2));
  float*          SP    = (float*)(ws + alc(512UL * 4096 * 4));
  unsigned short* Wbuf  = (unsigned short*)(ws + alc(128UL * 4096 * 2));
  float*          SSb   = (float*)(ws + alc(32768UL * 4));
  if (ws_size < off) return;

  // Dataflow (C always disjoint from A/B/resid) — identical to round 13.
  unsigned short* xb   = R0;
  unsigned short* HFb  = R0;
  unsigned short* QKb  = R1;
  unsigned short* H1b  = R2;
  float* outp = (float*)d_out;

  hipMemsetAsync(HBb, 0, 8192 * 4, stream);
  hipMemsetAsync(SSb, 0, 32768 * 4, stream);
  prep_kernel<<<17473, 256, 0, stream>>>(x, xb, Wq, Wk, Wv, Wo, W1, W2, bq, bk, bv, g1,
                                         BqkT, WoT, W1T, W2T, WvR, bqkv);
  // QK = xb @ [Wq|Wk]^T + b  (N=2048; grid 128x8 = 1024)
  gemm16w<0, 0, 0><<<1024, 1024, 65536, stream>>>(xb, 1024, BqkT, 1024, QKb, 2048,
                                                  bqkv, nullptr, 0, nullptr, nullptr,
                                                  1024, 8);
  scores_mfma<<<dim3(128, 4), 256, 0, stream>>>(QKb, SP);
  softmax_Wb<<<128, 64, 0, stream>>>(SP, mask, Wbuf);
  wpt_kernel<<<dim3(4, 16, 8), 256, 0, stream>>>(WoT, Wbuf, WPb, bqkv + 2048, HBb);
  // WVP_b = WPT_b @ WvR^T  (M=8192; grid 32x4 = 128)
  gemm16w<6, 0, 0><<<128, 1024, 65536, stream>>>(WPb, 1024, WvR, 1024, WVPb, 1024,
                                                 nullptr, nullptr, 0, nullptr, nullptr,
                                                 1024, 4);
  // h1 = xb + xb @ WVP_b^T + hb_b + bo ; SS atomics into SSb
  gemm16w<7, 1, 1><<<512, 1024, 65536, stream>>>(xb, 1024, WVPb, 1024, H1b, 1024,
                                                 HBb, xb, 1024, SSb, bo,
                                                 1024, 4);
  // t = tanh(rs * (h1 @ W1g^T) + b1)
  gemm_bt<4><<<dim3(1, 256), 256, 0, stream>>>(H1b, 1024, W1T, 1024, Tb, 128, b1, SSb, 1024);
  // hf = t@W2T + b2 + h1*rs*g1
  gemm16w<5, 0, 0><<<512, 1024, 65536, stream>>>(Tb, 128, W2T, 128, HFb, 1024,
                                                 b2, H1b, 1024, SSb, g1,
                                                 128, 4);
  rmsnorm_k<<<32768, 256, 0, stream>>>(HFb, g2, outp);
}

// Round 15
// 454.355 us; speedup vs baseline: 1.0534x; 1.0534x over previous
//
#include <hip/hip_runtime.h>
#include <math.h>

typedef __attribute__((ext_vector_type(4))) float f32x4;
typedef __attribute__((ext_vector_type(8))) short short8;   // 8 bf16 raw bits
typedef __attribute__((ext_vector_type(4))) short short4v;  // 4 bf16 raw bits

__device__ __forceinline__ float b2f(unsigned short u) {
  unsigned int x = ((unsigned int)u) << 16;
  return __builtin_bit_cast(float, x);
}
__device__ __forceinline__ unsigned short f2b(float f) {
  unsigned int x = __builtin_bit_cast(unsigned int, f);
  x += 0x7fffu + ((x >> 16) & 1u);   // round-to-nearest-even
  return (unsigned short)(x >> 16);
}

// async global->LDS, 16B per lane. LDS dest must be lane-contiguous (wave base + lane*16).
__device__ __forceinline__ void gload16(const unsigned short* g, unsigned short* l) {
  __builtin_amdgcn_global_load_lds(
      (__attribute__((address_space(1))) void*)(unsigned long long)(const void*)g,
      (__attribute__((address_space(3))) void*)l, 16, 0, 0);
}

#define BARR  { __builtin_amdgcn_sched_barrier(0); __builtin_amdgcn_s_barrier(); __builtin_amdgcn_sched_barrier(0); }
#define LBARR { __builtin_amdgcn_sched_barrier(0); asm volatile("s_waitcnt lgkmcnt(0)" ::: "memory"); __builtin_amdgcn_s_barrier(); __builtin_amdgcn_sched_barrier(0); }
// CROSS-WAVE RULE: vmcnt gate protecting a cooperatively-staged LDS buffer sits
// BEFORE the barrier preceding the reads. BUFFER RULE: a GEMM's C region must
// be disjoint from its A, B, and residual regions. REGISTER RULE (round 11):
// unified VGPR/AGPR file — acc[8][4]=128 regs/wave -> 2 waves/SIMD cap.
// LDS-BW RULE (round 14): fragment re-reads cap MfmaUtil at ~41% for this
// geometry; smaller wave tiles (v4) RAISE LDS bytes/FLOP and regress.
#define VMW(n) { __builtin_amdgcn_sched_barrier(0); asm volatile("s_waitcnt vmcnt(" #n ")" ::: "memory"); __builtin_amdgcn_sched_barrier(0); }

// ---------------------------------------------------------------------------
// prep_kernel: x->bf16 + weight repacks + bias concat (verified).
// ---------------------------------------------------------------------------
__global__ __launch_bounds__(256) void prep_kernel(
    const float* __restrict__ x, unsigned short* __restrict__ xb,
    const float* __restrict__ Wq, const float* __restrict__ Wk,
    const float* __restrict__ Wv, const float* __restrict__ Wo,
    const float* __restrict__ W1, const float* __restrict__ W2,
    const float* __restrict__ bq, const float* __restrict__ bk, const float* __restrict__ bv,
    const float* __restrict__ g1,
    unsigned short* __restrict__ BqkT, unsigned short* __restrict__ WoT,
    unsigned short* __restrict__ W1T, unsigned short* __restrict__ W2T,
    unsigned short* __restrict__ WvR,
    float* __restrict__ bqkv) {
  __shared__ float tile[64][65];
  int nb = blockIdx.x, t = threadIdx.x;
  if (nb < 16384) {
    long i = (long)nb * 256 + t;
    f32x4 a = ((const f32x4*)x)[i * 2];
    f32x4 b = ((const f32x4*)x)[i * 2 + 1];
    short8 o;
#pragma unroll
    for (int j = 0; j < 4; ++j) { o[j] = (short)f2b(a[j]); o[4 + j] = (short)f2b(b[j]); }
    ((short8*)xb)[i] = o;
    return;
  }
  int n0 = nb - 16384;
  if (n0 == 1088) {
#pragma unroll
    for (int it = 0; it < 12; ++it) {
      int idx = it * 256 + t;
      float v = (idx < 1024) ? bq[idx] : (idx < 2048 ? bk[idx - 1024] : bv[idx - 2048]);
      bqkv[idx] = v;
    }
    return;
  }
  if (n0 >= 832) {                        // WvR[d][h*64+e] = Wv[h][d][e] (copy+cvt)
    int rem = n0 - 832, h = rem >> 4, dc = rem & 15;
    int r = t >> 2, c0 = (t & 3) * 16;
    const float* s = Wv + ((long)h * 1024 + dc * 64 + r) * 64 + c0;
    unsigned short* d = WvR + (long)(dc * 64 + r) * 1024 + h * 64 + c0;
#pragma unroll
    for (int j4 = 0; j4 < 4; ++j4) {
      f32x4 v = *(const f32x4*)(s + j4 * 4);
      short4v o;
#pragma unroll
      for (int j = 0; j < 4; ++j) o[j] = (short)f2b(v[j]);
      *(short4v*)(d + j4 * 4) = o;
    }
    return;
  }
  const float* src; unsigned short* dst; int sld, dld;
  bool foldg = false; int dbase = 0;
  if (n0 < 512) {                         // Wq/Wk -> BqkT rows [w*1024 + h*64 + e]
    int w = n0 >> 8, rem = n0 & 255, h = rem >> 4, dc = rem & 15;
    const float* W = (w == 0) ? Wq : Wk;
    src = W + ((long)h * 1024 + dc * 64) * 64;                 sld = 64;
    dst = BqkT + (long)(w * 1024 + h * 64) * 1024 + dc * 64;   dld = 1024;
  } else if (n0 < 768) {
    int rem = n0 - 512, dr = rem >> 4, jc = rem & 15;
    src = Wo + (long)dr * 64 * 1024 + jc * 64;                 sld = 1024;
    dst = WoT + (long)jc * 64 * 1024 + dr * 64;                dld = 1024;
  } else if (n0 < 800) {
    int rem = n0 - 768, dr = rem >> 1, fc = rem & 1;
    src = W1 + (long)dr * 64 * 128 + fc * 64;                  sld = 128;
    dst = W1T + (long)fc * 64 * 1024 + dr * 64;                dld = 1024;
    foldg = true; dbase = dr * 64;
  } else {
    int rem = n0 - 800, fr = rem >> 4, jc = rem & 15;
    src = W2 + (long)fr * 64 * 1024 + jc * 64;                 sld = 1024;
    dst = W2T + (long)jc * 64 * 128 + fr * 64;                 dld = 128;
  }
  int r = t >> 2, c0 = (t & 3) * 16;
#pragma unroll
  for (int j4 = 0; j4 < 4; ++j4) {
    f32x4 v = *(const f32x4*)(src + (long)r * sld + c0 + j4 * 4);
    tile[c0 + j4 * 4 + 0][r] = v[0];
    tile[c0 + j4 * 4 + 1][r] = v[1];
    tile[c0 + j4 * 4 + 2][r] = v[2];
    tile[c0 + j4 * 4 + 3][r] = v[3];
  }
  __syncthreads();
  short8 o0, o1;
#pragma unroll
  for (int j = 0; j < 8; ++j) {
    float v0 = tile[r][c0 + j], v1 = tile[r][c0 + 8 + j];
    if (foldg) { v0 *= g1[dbase + c0 + j]; v1 *= g1[dbase + c0 + 8 + j]; }
    o0[j] = (short)f2b(v0);
    o1[j] = (short)f2b(v1);
  }
  *(short8*)(dst + (long)r * dld + c0) = o0;
  *(short8*)(dst + (long)r * dld + c0 + 8) = o1;
}

// ---------------------------------------------------------------------------
// 256x256 bf16 GEMM v2.3 (verified rounds 10/12/13): v2.1 schedule +
// generalized XCD grid mapping. BK=64, LDS 128KB, 1 block/CU.
// EPI: 0 = +bias ; 5 = +bias + h1*rs*g1 resid (rs from ssb inline) ;
//      6 = no bias ; 7 = +bias(per-batch) + bias2 + bf16 resid + row-SS atomics.
// BSEL: per-batch B (+(m0>>12)*1M). BBIAS: per-batch bias.
// ---------------------------------------------------------------------------
__device__ __forceinline__ void rdA2(short8 (&dst)[4][2], const char* paK0,
                                     const char* paK1, int off) {
#pragma unroll
  for (int fr = 0; fr < 4; ++fr) {
    dst[fr][0] = *(const short8*)(paK0 + off + fr * 2048);
    dst[fr][1] = *(const short8*)(paK1 + off + fr * 2048);
  }
}
__device__ __forceinline__ void rdB2(short8 (&dst)[2][2], const char* pbK0,
                                     const char* pbK1, int off) {
#pragma unroll
  for (int gr = 0; gr < 2; ++gr) {
    dst[gr][0] = *(const short8*)(pbK0 + off + gr * 2048);
    dst[gr][1] = *(const short8*)(pbK1 + off + gr * 2048);
  }
}
template <int BPH>
__device__ __forceinline__ void mfmaq_f(const short8 (&afr)[4][2], const short8 (&bf)[2][2],
                                        f32x4 (*ac)[4]) {
  __builtin_amdgcn_s_setprio(1);
#pragma unroll
  for (int fi = 0; fi < 4; ++fi)
#pragma unroll
    for (int gj = 0; gj < 2; ++gj)
#pragma unroll
      for (int ks = 0; ks < 2; ++ks)
        ac[fi][BPH * 2 + gj] = __builtin_amdgcn_mfma_f32_16x16x32_bf16(
            afr[fi][ks], bf[gj][ks], ac[fi][BPH * 2 + gj], 0, 0, 0);
  __builtin_amdgcn_s_setprio(0);
}

template <int EPI, int BSEL, int BBIAS>
__global__ __launch_bounds__(512, 2) void gemm8p(
    const unsigned short* __restrict__ A, int lda,
    const unsigned short* __restrict__ Bt, int ldb,
    unsigned short* __restrict__ C, int ldc,
    const float* __restrict__ bias,
    const unsigned short* __restrict__ residb, int ldr,
    float* __restrict__ ssb, const float* __restrict__ aux,
    int K, int NBX) {
  extern __shared__ char smb[];
  const int tid = threadIdx.x;
  const int lane = tid & 63, wid = tid >> 6;
  const int wm = wid >> 2, wn = wid & 3;

  int orig = blockIdx.x;
  int xcd = orig & 7, j = orig >> 3;
  int perx = gridDim.x >> 3;
  int mpx = perx / NBX;
  int ms = j / (4 * NBX), nb = (j >> 2) % NBX, mq = j & 3;
  const long m0 = (long)(xcd * mpx + ms * 4 + mq) * 256;
  const long n0 = (long)nb * 256;
  const unsigned short* bt = BSEL ? (Bt + (m0 >> 12) * 1048576) : Bt;
  const float* biasp = BBIAS ? (bias + (m0 >> 12) * 1024) : bias;

  const int NT = K >> 6, NI = NT >> 1;   // NT even for all our shapes

  const int lr = lane & 15, lc = (lane >> 4) * 16;
  const int eA = lc ^ ((lr & 7) << 4);
  const char* paK0 = smb + wm * 8192 + lr * 128 + eA;
  const char* paK1 = smb + wm * 8192 + lr * 128 + (eA ^ 64);
  const char* pbK0 = smb + 65536 + wn * 4096 + lr * 128 + eA;
  const char* pbK1 = smb + 65536 + wn * 4096 + lr * 128 + (eA ^ 64);

  short8 afr0[4][2], afr1[4][2];
  short8 bfr0[2][2], bfr1[2][2];
  f32x4 acc[8][4] = {};

  auto stA = [&](int buf, int ph, int kt) {
#pragma unroll
    for (int rnd = 0; rnd < 2; ++rnd) {
      int o = rnd * 8192 + tid * 16;
      int wms = o >> 13, rsw = (o >> 7) & 63, cb = o & 127;
      int pcb = cb ^ ((rsw & 7) << 4);
      const unsigned short* src = A + (m0 + wms * 128 + ph * 64 + rsw) * (long)lda + kt * 64 + (pcb >> 1);
      gload16(src, (unsigned short*)(smb + buf * 32768 + ph * 16384 + o));
    }
  };
  auto stB = [&](int buf, int ph, int kt) {
#pragma unroll
    for (int rnd = 0; rnd < 2; ++rnd) {
      int o = rnd * 8192 + tid * 16;
      int wns = (o >> 12) & 3, rsw = (o >> 7) & 31, cb = o & 127;
      int pcb = cb ^ ((rsw & 7) << 4);
      const unsigned short* src = bt + (n0 + wns * 64 + ph * 32 + rsw) * (long)ldb + kt * 64 + (pcb >> 1);
      gload16(src, (unsigned short*)(smb + 65536 + buf * 32768 + ph * 16384 + o));
    }
  };

  stA(0, 0, 0); stA(0, 1, 0); stB(0, 0, 0); stB(0, 1, 0);
  stA(1, 0, 1); stA(1, 1, 1); stB(1, 0, 1); stB(1, 1, 1);
  VMW(8);
  BARR;
  rdA2(afr0, paK0, paK1, 0);
  rdB2(bfr0, pbK0, pbK1, 0);

  for (int i = 0; i < NI; ++i) {
    int t2 = 2 * i + 2, t3 = 2 * i + 3;
    bool more = t2 < NT;
    // ---- tile 2i (buf0) ----
    LBARR;
    rdB2(bfr1, pbK0, pbK1, 16384);
    mfmaq_f<0>(afr0, bfr0, &acc[0]);
    LBARR;
    rdA2(afr1, paK0, paK1, 16384);
    mfmaq_f<1>(afr0, bfr1, &acc[0]);
    LBARR;
    if (more) { stA(0, 0, t2); stA(0, 1, t2); }
    mfmaq_f<0>(afr1, bfr0, &acc[4]);
    if (more) { VMW(4); } else { VMW(0); }
    LBARR;
    rdA2(afr0, paK0, paK1, 32768);
    rdB2(bfr0, pbK0, pbK1, 32768);
    if (more) { stB(0, 0, t2); stB(0, 1, t2); }
    mfmaq_f<1>(afr1, bfr1, &acc[4]);
    // ---- tile 2i+1 (buf1) ----
    LBARR;
    rdB2(bfr1, pbK0, pbK1, 32768 + 16384);
    mfmaq_f<0>(afr0, bfr0, &acc[0]);
    LBARR;
    rdA2(afr1, paK0, paK1, 32768 + 16384);
    mfmaq_f<1>(afr0, bfr1, &acc[0]);
    LBARR;
    if (more) { stA(1, 0, t3); stA(1, 1, t3); }
    mfmaq_f<0>(afr1, bfr0, &acc[4]);
    if (more) { VMW(4); } else { VMW(0); }
    LBARR;
    if (more) { rdA2(afr0, paK0, paK1, 0); rdB2(bfr0, pbK0, pbK1, 0); }
    if (more) { stB(1, 0, t3); stB(1, 1, t3); }
    mfmaq_f<1>(afr1, bfr1, &acc[4]);
  }

  // Epilogue. EPI7 accumulates per-row sum-of-squares into ssb.
#pragma unroll
  for (int f = 0; f < 8; ++f) {
    float ssp[4] = {0.0f, 0.0f, 0.0f, 0.0f};
#pragma unroll
    for (int g = 0; g < 4; ++g) {
      long col = n0 + wn * 64 + g * 16 + (lane & 15);
      float bv = (EPI == 6) ? 0.0f : biasp[col];
      if (EPI == 7) bv += aux[col];              // aux = bo
      float gv = (EPI == 5) ? aux[col] : 0.0f;   // aux = g1
#pragma unroll
      for (int r = 0; r < 4; ++r) {
        long row = m0 + wm * 128 + f * 16 + (lane >> 4) * 4 + r;
        float o = acc[f][g][r] + bv;
        if (EPI == 7) o += b2f(residb[row * (long)ldr + col]);
        if (EPI == 5) {
          float rsv = rsqrtf(ssb[row] * (1.0f / 1024.0f) + 1e-6f);
          o += b2f(residb[row * (long)ldr + col]) * rsv * gv;
        }
        if (EPI == 7) ssp[r] += o * o;
        C[row * (long)ldc + col] = f2b(o);
      }
    }
    if (EPI == 7) {
#pragma unroll
      for (int r = 0; r < 4; ++r) {
        float p = ssp[r];
        p += __shfl_xor(p, 1, 64);
        p += __shfl_xor(p, 2, 64);
        p += __shfl_xor(p, 4, 64);
        p += __shfl_xor(p, 8, 64);
        if ((lane & 15) == 0) {
          long row = m0 + wm * 128 + f * 16 + (lane >> 4) * 4 + r;
          atomicAdd(&ssb[row], p);
        }
      }
    }
  }
}

// ---------------------------------------------------------------------------
// m97-structure GEMM for FF1 (N=128). EPI 4: o = tanh(rs(ssb[row])*acc + bias).
// ---------------------------------------------------------------------------
template <int EPI>
__global__ __launch_bounds__(256, 2) void gemm_bt(
    const unsigned short* __restrict__ A, int lda,
    const unsigned short* __restrict__ Bt, int ldb,
    unsigned short* __restrict__ C, int ldc,
    const float* __restrict__ bias, const float* __restrict__ ssb, int K) {
  __shared__ __align__(16) unsigned short Asm[128 * 32];
  __shared__ __align__(16) unsigned short Bsm[128 * 32];
  const int tid = threadIdx.x;
  const int lane = tid & 63, wid = tid >> 6;
  const int wr = wid >> 1, wc = wid & 1;
  const long m0 = (long)blockIdx.y * 128;
  const long n0 = (long)blockIdx.x * 128;

  f32x4 acc[4][4] = {};

  for (int kk = 0; kk < K; kk += 32) {
    __syncthreads();
#pragma unroll
    for (int i = 0; i < 2; ++i) {
      int slot = i * 256 + tid;
      int r = slot >> 2, cg = (slot & 3) * 8;
      gload16(A + (m0 + r) * (long)lda + kk + cg, &Asm[slot * 8]);
      gload16(Bt + (n0 + r) * (long)ldb + kk + cg, &Bsm[slot * 8]);
    }
    __syncthreads();
    short8 af[4], bfr[4];
#pragma unroll
    for (int mt = 0; mt < 4; ++mt)
      af[mt] = *(const short8*)&Asm[(wr * 64 + mt * 16 + (lane & 15)) * 32 + (lane >> 4) * 8];
#pragma unroll
    for (int nt = 0; nt < 4; ++nt)
      bfr[nt] = *(const short8*)&Bsm[(wc * 64 + nt * 16 + (lane & 15)) * 32 + (lane >> 4) * 8];
#pragma unroll
    for (int mt = 0; mt < 4; ++mt)
#pragma unroll
      for (int nt = 0; nt < 4; ++nt)
        acc[mt][nt] = __builtin_amdgcn_mfma_f32_16x16x32_bf16(af[mt], bfr[nt], acc[mt][nt], 0, 0, 0);
  }

  const long row0 = m0 + wr * 64 + ((lane >> 4) * 4);
  const long col0 = n0 + wc * 64 + (lane & 15);
#pragma unroll
  for (int mt = 0; mt < 4; ++mt) {
#pragma unroll
    for (int nt = 0; nt < 4; ++nt) {
      long col = col0 + nt * 16;
      float bv = bias[col];
      f32x4 v = acc[mt][nt];
#pragma unroll
      for (int r = 0; r < 4; ++r) {
        long row = row0 + mt * 16 + r;
        float o = v[r];
        if (EPI == 4) {
          float rsv = rsqrtf(ssb[row] * (1.0f / 1024.0f) + 1e-6f);
          o = tanhf(o * rsv + bv);
        } else o += bv;
        C[row * (long)ldc + col] = f2b(o);
      }
    }
  }
}

// ---------------------------------------------------------------------------
// scores via MFMA (verified rounds 5-13); QK buffer stride 2048.
// ---------------------------------------------------------------------------
__device__ __forceinline__ int sperm(int e) { return ((e + (e >> 3)) & 7) << 4; }

__global__ __launch_bounds__(256) void scores_mfma(
    const unsigned short* __restrict__ QK, float* __restrict__ part) {
  __shared__ __align__(16) char lds[32768];
  int bh = blockIdx.x, seg = blockIdx.y;
  int b = bh >> 4, h = bh & 15;
  int tid = threadIdx.x, lane = tid & 63, wid = tid >> 6;
  int e0 = (tid & 7) * 8;
  int sl0 = (tid >> 3) * 4;
  const unsigned short* Qg = QK + h * 64;
  const unsigned short* Kg = QK + 1024 + h * 64;
  f32x4 acc[4] = {};

  for (int ch = 0; ch < 8; ++ch) {
    long S0 = (long)b * 4096 + seg * 1024 + ch * 128;
    __syncthreads();
    short8 kv0 = *(const short8*)(Kg + (S0 + sl0 + 0) * 2048 + e0);
    short8 kv1 = *(const short8*)(Kg + (S0 + sl0 + 1) * 2048 + e0);
    short8 kv2 = *(const short8*)(Kg + (S0 + sl0 + 2) * 2048 + e0);
    short8 kv3 = *(const short8*)(Kg + (S0 + sl0 + 3) * 2048 + e0);
    short8 qv0 = *(const short8*)(Qg + (S0 + sl0 + 0) * 2048 + e0);
    short8 qv1 = *(const short8*)(Qg + (S0 + sl0 + 1) * 2048 + e0);
    short8 qv2 = *(const short8*)(Qg + (S0 + sl0 + 2) * 2048 + e0);
    short8 qv3 = *(const short8*)(Qg + (S0 + sl0 + 3) * 2048 + e0);
#pragma unroll
    for (int je = 0; je < 8; ++je) {
      int e = e0 + je;
      int sw = sperm(e);
      char* rowK = lds + e * 256;
      char* rowQ = lds + 16384 + e * 256;
      unsigned int klo = (unsigned short)kv0[je] | ((unsigned int)(unsigned short)kv1[je] << 16);
      unsigned int khi = (unsigned short)kv2[je] | ((unsigned int)(unsigned short)kv3[je] << 16);
      unsigned int qlo = (unsigned short)qv0[je] | ((unsigned int)(unsigned short)qv1[je] << 16);
      unsigned int qhi = (unsigned short)qv2[je] | ((unsigned int)(unsigned short)qv3[je] << 16);
      *(unsigned int*)(rowK + ((sl0 * 2) ^ sw)) = klo;
      *(unsigned int*)(rowK + ((sl0 * 2 + 4) ^ sw)) = khi;
      *(unsigned int*)(rowQ + ((sl0 * 2) ^ sw)) = qlo;
      *(unsigned int*)(rowQ + ((sl0 * 2 + 4) ^ sw)) = qhi;
    }
    __syncthreads();
#pragma unroll
    for (int ksi = 0; ksi < 4; ++ksi) {
      int colb = ksi * 64 + (lane >> 4) * 16;
      int erA = wid * 16 + (lane & 15);
      short8 af = *(const short8*)(lds + erA * 256 + (colb ^ sperm(erA)));
#pragma unroll
      for (int n = 0; n < 4; ++n) {
        int erB = n * 16 + (lane & 15);
        short8 bf = *(const short8*)(lds + 16384 + erB * 256 + (colb ^ sperm(erB)));
        acc[n] = __builtin_amdgcn_mfma_f32_16x16x32_bf16(af, bf, acc[n], 0, 0, 0);
      }
    }
  }
  float* dst = part + ((long)bh * 4 + seg) * 4096;
#pragma unroll
  for (int n = 0; n < 4; ++n)
#pragma unroll
    for (int r = 0; r < 4; ++r) {
      int k = wid * 16 + (lane >> 4) * 4 + r;
      int q = n * 16 + (lane & 15);
      dst[k * 64 + q] = acc[n][r];
    }
}

// softmax over k (per q column), scores/8; writes w row-major: Wb[bh][k][q]
__global__ __launch_bounds__(64) void softmax_Wb(
    const float* __restrict__ part, const int* __restrict__ mask,
    unsigned short* __restrict__ Wb) {
  __shared__ float lt[64][65];
  int bh = blockIdx.x, q = threadIdx.x;
  int b = bh >> 4;
  const float* p0 = part + (long)bh * 4 * 4096;
  float s[64];
#pragma unroll
  for (int k = 0; k < 64; ++k)
    s[k] = p0[k * 64 + q] + p0[4096 + k * 64 + q] + p0[8192 + k * 64 + q] + p0[12288 + k * 64 + q];
  bool live = (mask[b * 64 + q] != 0);
  float m = -1e30f;
#pragma unroll
  for (int k = 0; k < 64; ++k) m = fmaxf(m, s[k]);
  float sum = 0.0f;
#pragma unroll
  for (int k = 0; k < 64; ++k) {
    s[k] = __expf((s[k] - m) * 0.125f);
    sum += s[k];
  }
  float inv = live ? 1.0f / sum : 0.0f;
#pragma unroll
  for (int k = 0; k < 64; ++k) lt[k][q] = s[k] * inv;
  __syncthreads();
  unsigned short* o = Wb + (long)bh * 4096 + q * 64;
#pragma unroll
  for (int j8 = 0; j8 < 8; ++j8) {
    short8 ov;
#pragma unroll
    for (int j = 0; j < 8; ++j) ov[j] = (short)f2b(lt[q][j8 * 8 + j]);
    *(short8*)(o + j8 * 8) = ov;
  }
}

// WPT[b][d][h*64+k] = sum_q Wo[h*64+q][d] * w_bh[k][q]
// Fused: atomicAdd partial of hb[b][d] = sum_col WPT[d][col]*bv[col].
__global__ __launch_bounds__(256) void wpt_kernel(
    const unsigned short* __restrict__ WoT, const unsigned short* __restrict__ Wb,
    unsigned short* __restrict__ WPT, const float* __restrict__ bv,
    float* __restrict__ hb) {
  int dblk = blockIdx.x;   // 4
  int h = blockIdx.y;      // 16
  int b = blockIdx.z;      // 8
  int tid = threadIdx.x, lane = tid & 63, wid = tid >> 6;
  int d0 = dblk * 256 + wid * 64;
  const unsigned short* wb = Wb + (long)(b * 16 + h) * 4096;
  f32x4 acc[4][4] = {};
#pragma unroll
  for (int ks = 0; ks < 2; ++ks) {
    short8 bf[4];
#pragma unroll
    for (int nt = 0; nt < 4; ++nt)
      bf[nt] = *(const short8*)(wb + (nt * 16 + (lane & 15)) * 64 + ks * 32 + (lane >> 4) * 8);
#pragma unroll
    for (int mt = 0; mt < 4; ++mt) {
      short8 af = *(const short8*)(WoT + (long)(d0 + mt * 16 + (lane & 15)) * 1024 + h * 64 + ks * 32 + (lane >> 4) * 8);
#pragma unroll
      for (int nt = 0; nt < 4; ++nt)
        acc[mt][nt] = __builtin_amdgcn_mfma_f32_16x16x32_bf16(af, bf[nt], acc[mt][nt], 0, 0, 0);
    }
  }
  float bvv[4];
#pragma unroll
  for (int nt = 0; nt < 4; ++nt) bvv[nt] = bv[h * 64 + nt * 16 + (lane & 15)];
#pragma unroll
  for (int mt = 0; mt < 4; ++mt) {
#pragma unroll
    for (int r = 0; r < 4; ++r) {
      long row = d0 + mt * 16 + (lane >> 4) * 4 + r;
      float p = 0.0f;
#pragma unroll
      for (int nt = 0; nt < 4; ++nt) {
        float o = acc[mt][nt][r];
        WPT[(long)b * 1048576 + row * 1024 + h * 64 + nt * 16 + (lane & 15)] = f2b(o);
        p += o * bvv[nt];
      }
      p += __shfl_xor(p, 1, 64);
      p += __shfl_xor(p, 2, 64);
      p += __shfl_xor(p, 4, 64);
      p += __shfl_xor(p, 8, 64);
      if ((lane & 15) == 0) atomicAdd(&hb[b * 1024 + row], p);
    }
  }
}

// rmsnorm over D=1024; one block per row. bf16 in; f32 out.
__global__ __launch_bounds__(256) void rmsnorm_k(
    const unsigned short* __restrict__ in, const float* __restrict__ g,
    float* __restrict__ outf) {
  long row = blockIdx.x;
  int tid = threadIdx.x;
  short4v u = *(const short4v*)(in + row * 1024 + tid * 4);
  float v[4];
  float ss = 0.0f;
#pragma unroll
  for (int i = 0; i < 4; ++i) {
    v[i] = b2f((unsigned short)u[i]);
    ss += v[i] * v[i];
  }
#pragma unroll
  for (int off = 32; off > 0; off >>= 1) ss += __shfl_xor(ss, off, 64);
  __shared__ float wsum[4];
  if ((tid & 63) == 0) wsum[tid >> 6] = ss;
  __syncthreads();
  float tot = wsum[0] + wsum[1] + wsum[2] + wsum[3];
  float rsv = rsqrtf(tot * (1.0f / 1024.0f) + 1e-6f);
  f32x4 gv = *(const f32x4*)(g + tid * 4);
  f32x4 ov;
#pragma unroll
  for (int i = 0; i < 4; ++i) ov[i] = v[i] * rsv * gv[i];
  *(f32x4*)(outf + row * 1024 + tid * 4) = ov;
}

// ---------------------------------------------------------------------------
extern "C" void kernel_launch(void* const* d_in, const int* in_sizes, int n_in,
                              void* d_out, int out_size, void* d_ws, size_t ws_size,
                              hipStream_t stream) {
  const float* x  = (const float*)d_in[0];
  const int* mask = (const int*)d_in[1];
  const float* Wq = (const float*)d_in[2];
  const float* bq = (const float*)d_in[3];
  const float* Wk = (const float*)d_in[4];
  const float* bk = (const float*)d_in[5];
  const float* Wv = (const float*)d_in[6];
  const float* bv = (const float*)d_in[7];
  const float* Wo = (const float*)d_in[8];
  const float* bo = (const float*)d_in[9];
  const float* W1 = (const float*)d_in[10];
  const float* b1 = (const float*)d_in[11];
  const float* W2 = (const float*)d_in[12];
  const float* b2 = (const float*)d_in[13];
  const float* g1 = (const float*)d_in[14];
  const float* g2 = (const float*)d_in[15];

  char* ws = (char*)d_ws;
  size_t off = 0;
  auto alc = [&](size_t n) { size_t o = off; off += (n + 255) & ~(size_t)255; return o; };
  unsigned short* BqkT  = (unsigned short*)(ws + alc(2048UL * 1024 * 2));
  unsigned short* WoT   = (unsigned short*)(ws + alc(1024UL * 1024 * 2));
  unsigned short* W1T   = (unsigned short*)(ws + alc(128UL * 1024 * 2));    // g1-folded
  unsigned short* W2T   = (unsigned short*)(ws + alc(1024UL * 128 * 2));
  unsigned short* WvR   = (unsigned short*)(ws + alc(1024UL * 1024 * 2));
  float*          bqkv  = (float*)(ws + alc(3072UL * 4));
  float*          HBb   = (float*)(ws + alc(8192UL * 4));
  unsigned short* R0    = (unsigned short*)(ws + alc(32768UL * 1024 * 2));  // xb -> hf
  unsigned short* R1    = (unsigned short*)(ws + alc(32768UL * 2048 * 2));  // QK
  unsigned short* R2    = (unsigned short*)(ws + alc(32768UL * 1024 * 2));  // h1
  unsigned short* WPb   = (unsigned short*)(ws + alc(8UL * 1048576 * 2));   // WPT
  unsigned short* WVPb  = (unsigned short*)(ws + alc(8UL * 1048576 * 2));   // WVP
  unsigned short* Tb    = (unsigned short*)(ws + alc(32768UL * 128 * 2));
  float*          SP    = (float*)(ws + alc(512UL * 4096 * 4));
  unsigned short* Wbuf  = (unsigned short*)(ws + alc(128UL * 4096 * 2));
  float*          SSb   = (float*)(ws + alc(32768UL * 4));
  if (ws_size < off) return;

  // Dataflow (C always disjoint from A/B/resid):
  //   prep:   x -> xb(R0); weights; bqkv
  //   QK:     xb(R0) @ BqkT -> QK(R1)                 [EPI0]
  //   scores: QK(R1) -> SP ; softmax -> Wbuf
  //   wpt:    -> WPT(WPb) + atomics hb(HBb, pre-zeroed)
  //   WVP:    WPT @ WvR -> WVP(WVPb)                  [EPI6]
  //   h1:     xb @ WVP_b + hb_b + bo + xb -> h1(R2)   [EPI7; SS atomics -> SSb]
  //   FF1:    h1 @ W1g, tanh(rs(SSb)*acc+b1) -> t(Tb) [EPI4]
  //   FF2:    t @ W2T + b2 + h1*rs(SSb)*g1 -> hf(R0)  [EPI5; xb dead]
  //   rms2:   hf(R0) -> out
  unsigned short* xb   = R0;
  unsigned short* HFb  = R0;
  unsigned short* QKb  = R1;
  unsigned short* H1b  = R2;
  float* outp = (float*)d_out;

  hipMemsetAsync(HBb, 0, 8192 * 4, stream);
  hipMemsetAsync(SSb, 0, 32768 * 4, stream);
  prep_kernel<<<17473, 256, 0, stream>>>(x, xb, Wq, Wk, Wv, Wo, W1, W2, bq, bk, bv, g1,
                                         BqkT, WoT, W1T, W2T, WvR, bqkv);
  // QK = xb @ [Wq|Wk]^T + b  (N=2048; grid 128x8 = 1024)
  gemm8p<0, 0, 0><<<1024, 512, 131072, stream>>>(xb, 1024, BqkT, 1024, QKb, 2048,
                                                 bqkv, nullptr, 0, nullptr, nullptr,
                                                 1024, 8);
  scores_mfma<<<dim3(128, 4), 256, 0, stream>>>(QKb, SP);
  softmax_Wb<<<128, 64, 0, stream>>>(SP, mask, Wbuf);
  wpt_kernel<<<dim3(4, 16, 8), 256, 0, stream>>>(WoT, Wbuf, WPb, bqkv + 2048, HBb);
  // WVP_b = WPT_b @ WvR^T  (M=8192; grid 32x4 = 128)
  gemm8p<6, 0, 0><<<128, 512, 131072, stream>>>(WPb, 1024, WvR, 1024, WVPb, 1024,
                                                nullptr, nullptr, 0, nullptr, nullptr,
                                                1024, 4);
  // h1 = xb + xb @ WVP_b^T + hb_b + bo ; SS atomics into SSb
  gemm8p<7, 1, 1><<<512, 512, 131072, stream>>>(xb, 1024, WVPb, 1024, H1b, 1024,
                                                HBb, xb, 1024, SSb, bo,
                                                1024, 4);
  // t = tanh(rs * (h1 @ W1g^T) + b1)
  gemm_bt<4><<<dim3(1, 256), 256, 0, stream>>>(H1b, 1024, W1T, 1024, Tb, 128, b1, SSb, 1024);
  // hf = t@W2T + b2 + h1*rs*g1
  gemm8p<5, 0, 0><<<512, 512, 131072, stream>>>(Tb, 128, W2T, 128, HFb, 1024,
                                                b2, H1b, 1024, SSb, g1,
                                                128, 4);
  rmsnorm_k<<<32768, 256, 0, stream>>>(HFb, g2, outp);
}

// Round 16
// 447.143 us; speedup vs baseline: 1.0704x; 1.0161x over previous
//
#include <hip/hip_runtime.h>
#include <math.h>

typedef __attribute__((ext_vector_type(4))) float f32x4;
typedef __attribute__((ext_vector_type(8))) short short8;   // 8 bf16 raw bits
typedef __attribute__((ext_vector_type(4))) short short4v;  // 4 bf16 raw bits

__device__ __forceinline__ float b2f(unsigned short u) {
  unsigned int x = ((unsigned int)u) << 16;
  return __builtin_bit_cast(float, x);
}
__device__ __forceinline__ unsigned short f2b(float f) {
  unsigned int x = __builtin_bit_cast(unsigned int, f);
  x += 0x7fffu + ((x >> 16) & 1u);   // round-to-nearest-even
  return (unsigned short)(x >> 16);
}

// async global->LDS, 16B per lane. LDS dest must be lane-contiguous (wave base + lane*16).
__device__ __forceinline__ void gload16(const unsigned short* g, unsigned short* l) {
  __builtin_amdgcn_global_load_lds(
      (__attribute__((address_space(1))) void*)(unsigned long long)(const void*)g,
      (__attribute__((address_space(3))) void*)l, 16, 0, 0);
}

#define BARR  { __builtin_amdgcn_sched_barrier(0); __builtin_amdgcn_s_barrier(); __builtin_amdgcn_sched_barrier(0); }
#define LBARR { __builtin_amdgcn_sched_barrier(0); asm volatile("s_waitcnt lgkmcnt(0)" ::: "memory"); __builtin_amdgcn_s_barrier(); __builtin_amdgcn_sched_barrier(0); }
// CROSS-WAVE RULE: vmcnt gate protecting a cooperatively-staged LDS buffer sits
// BEFORE the barrier preceding the reads. BUFFER RULE: a GEMM's C region must
// be disjoint from its A, B, and residual regions. REGISTER RULE (round 11):
// unified VGPR/AGPR file — acc[8][4]=128 regs/wave -> 2 waves/SIMD cap.
// LDS-BW RULE (round 14): fragment re-reads cap MfmaUtil at ~41% for this
// geometry. OCCUPANCY RULE (round 16): prefer the GEMM variant whose grid
// fills all 256 CUs — gemm8p (256^2) for M>=128K-tiles, gemm_bt (128^2,
// 2 blocks/CU) for mid-size M like 8192.
#define VMW(n) { __builtin_amdgcn_sched_barrier(0); asm volatile("s_waitcnt vmcnt(" #n ")" ::: "memory"); __builtin_amdgcn_sched_barrier(0); }

// ---------------------------------------------------------------------------
// prep_kernel: x->bf16 + weight repacks + bias concat + HBb/SSb zeroing.
// Grid: [0,16384) cvt ; [16384,16384+1091) weights/bias/zero blocks.
// ---------------------------------------------------------------------------
__global__ __launch_bounds__(256) void prep_kernel(
    const float* __restrict__ x, unsigned short* __restrict__ xb,
    const float* __restrict__ Wq, const float* __restrict__ Wk,
    const float* __restrict__ Wv, const float* __restrict__ Wo,
    const float* __restrict__ W1, const float* __restrict__ W2,
    const float* __restrict__ bq, const float* __restrict__ bk, const float* __restrict__ bv,
    const float* __restrict__ g1,
    unsigned short* __restrict__ BqkT, unsigned short* __restrict__ WoT,
    unsigned short* __restrict__ W1T, unsigned short* __restrict__ W2T,
    unsigned short* __restrict__ WvR,
    float* __restrict__ bqkv,
    float* __restrict__ HBz, float* __restrict__ SSz) {
  __shared__ float tile[64][65];
  int nb = blockIdx.x, t = threadIdx.x;
  if (nb < 16384) {
    long i = (long)nb * 256 + t;
    f32x4 a = ((const f32x4*)x)[i * 2];
    f32x4 b = ((const f32x4*)x)[i * 2 + 1];
    short8 o;
#pragma unroll
    for (int j = 0; j < 4; ++j) { o[j] = (short)f2b(a[j]); o[4 + j] = (short)f2b(b[j]); }
    ((short8*)xb)[i] = o;
    return;
  }
  int n0 = nb - 16384;
  if (n0 == 1088) {
#pragma unroll
    for (int it = 0; it < 12; ++it) {
      int idx = it * 256 + t;
      float v = (idx < 1024) ? bq[idx] : (idx < 2048 ? bk[idx - 1024] : bv[idx - 2048]);
      bqkv[idx] = v;
    }
    return;
  }
  if (n0 == 1089) {                       // zero HBb (8192 f32)
#pragma unroll
    for (int it = 0; it < 32; ++it) HBz[it * 256 + t] = 0.0f;
    return;
  }
  if (n0 == 1090) {                       // zero SSb (32768 f32)
#pragma unroll
    for (int it = 0; it < 128; ++it) SSz[it * 256 + t] = 0.0f;
    return;
  }
  if (n0 >= 832) {                        // WvR[d][h*64+e] = Wv[h][d][e] (copy+cvt)
    int rem = n0 - 832, h = rem >> 4, dc = rem & 15;
    int r = t >> 2, c0 = (t & 3) * 16;
    const float* s = Wv + ((long)h * 1024 + dc * 64 + r) * 64 + c0;
    unsigned short* d = WvR + (long)(dc * 64 + r) * 1024 + h * 64 + c0;
#pragma unroll
    for (int j4 = 0; j4 < 4; ++j4) {
      f32x4 v = *(const f32x4*)(s + j4 * 4);
      short4v o;
#pragma unroll
      for (int j = 0; j < 4; ++j) o[j] = (short)f2b(v[j]);
      *(short4v*)(d + j4 * 4) = o;
    }
    return;
  }
  const float* src; unsigned short* dst; int sld, dld;
  bool foldg = false; int dbase = 0;
  if (n0 < 512) {                         // Wq/Wk -> BqkT rows [w*1024 + h*64 + e]
    int w = n0 >> 8, rem = n0 & 255, h = rem >> 4, dc = rem & 15;
    const float* W = (w == 0) ? Wq : Wk;
    src = W + ((long)h * 1024 + dc * 64) * 64;                 sld = 64;
    dst = BqkT + (long)(w * 1024 + h * 64) * 1024 + dc * 64;   dld = 1024;
  } else if (n0 < 768) {
    int rem = n0 - 512, dr = rem >> 4, jc = rem & 15;
    src = Wo + (long)dr * 64 * 1024 + jc * 64;                 sld = 1024;
    dst = WoT + (long)jc * 64 * 1024 + dr * 64;                dld = 1024;
  } else if (n0 < 800) {
    int rem = n0 - 768, dr = rem >> 1, fc = rem & 1;
    src = W1 + (long)dr * 64 * 128 + fc * 64;                  sld = 128;
    dst = W1T + (long)fc * 64 * 1024 + dr * 64;                dld = 1024;
    foldg = true; dbase = dr * 64;
  } else {
    int rem = n0 - 800, fr = rem >> 4, jc = rem & 15;
    src = W2 + (long)fr * 64 * 1024 + jc * 64;                 sld = 1024;
    dst = W2T + (long)jc * 64 * 128 + fr * 64;                 dld = 128;
  }
  int r = t >> 2, c0 = (t & 3) * 16;
#pragma unroll
  for (int j4 = 0; j4 < 4; ++j4) {
    f32x4 v = *(const f32x4*)(src + (long)r * sld + c0 + j4 * 4);
    tile[c0 + j4 * 4 + 0][r] = v[0];
    tile[c0 + j4 * 4 + 1][r] = v[1];
    tile[c0 + j4 * 4 + 2][r] = v[2];
    tile[c0 + j4 * 4 + 3][r] = v[3];
  }
  __syncthreads();
  short8 o0, o1;
#pragma unroll
  for (int j = 0; j < 8; ++j) {
    float v0 = tile[r][c0 + j], v1 = tile[r][c0 + 8 + j];
    if (foldg) { v0 *= g1[dbase + c0 + j]; v1 *= g1[dbase + c0 + 8 + j]; }
    o0[j] = (short)f2b(v0);
    o1[j] = (short)f2b(v1);
  }
  *(short8*)(dst + (long)r * dld + c0) = o0;
  *(short8*)(dst + (long)r * dld + c0 + 8) = o1;
}

// ---------------------------------------------------------------------------
// 256x256 bf16 GEMM v2.3 (verified rounds 10/12/13/15): v2.1 schedule +
// generalized XCD grid mapping. BK=64, LDS 128KB, 1 block/CU.
// EPI: 0 = +bias ; 5 = +bias + h1*rs*g1 resid (rs from ssb inline) ;
//      6 = no bias ; 7 = +bias(per-batch) + bias2 + bf16 resid + row-SS atomics.
// BSEL: per-batch B (+(m0>>12)*1M). BBIAS: per-batch bias.
// ---------------------------------------------------------------------------
__device__ __forceinline__ void rdA2(short8 (&dst)[4][2], const char* paK0,
                                     const char* paK1, int off) {
#pragma unroll
  for (int fr = 0; fr < 4; ++fr) {
    dst[fr][0] = *(const short8*)(paK0 + off + fr * 2048);
    dst[fr][1] = *(const short8*)(paK1 + off + fr * 2048);
  }
}
__device__ __forceinline__ void rdB2(short8 (&dst)[2][2], const char* pbK0,
                                     const char* pbK1, int off) {
#pragma unroll
  for (int gr = 0; gr < 2; ++gr) {
    dst[gr][0] = *(const short8*)(pbK0 + off + gr * 2048);
    dst[gr][1] = *(const short8*)(pbK1 + off + gr * 2048);
  }
}
template <int BPH>
__device__ __forceinline__ void mfmaq_f(const short8 (&afr)[4][2], const short8 (&bf)[2][2],
                                        f32x4 (*ac)[4]) {
  __builtin_amdgcn_s_setprio(1);
#pragma unroll
  for (int fi = 0; fi < 4; ++fi)
#pragma unroll
    for (int gj = 0; gj < 2; ++gj)
#pragma unroll
      for (int ks = 0; ks < 2; ++ks)
        ac[fi][BPH * 2 + gj] = __builtin_amdgcn_mfma_f32_16x16x32_bf16(
            afr[fi][ks], bf[gj][ks], ac[fi][BPH * 2 + gj], 0, 0, 0);
  __builtin_amdgcn_s_setprio(0);
}

template <int EPI, int BSEL, int BBIAS>
__global__ __launch_bounds__(512, 2) void gemm8p(
    const unsigned short* __restrict__ A, int lda,
    const unsigned short* __restrict__ Bt, int ldb,
    unsigned short* __restrict__ C, int ldc,
    const float* __restrict__ bias,
    const unsigned short* __restrict__ residb, int ldr,
    float* __restrict__ ssb, const float* __restrict__ aux,
    int K, int NBX) {
  extern __shared__ char smb[];
  const int tid = threadIdx.x;
  const int lane = tid & 63, wid = tid >> 6;
  const int wm = wid >> 2, wn = wid & 3;

  int orig = blockIdx.x;
  int xcd = orig & 7, j = orig >> 3;
  int perx = gridDim.x >> 3;
  int mpx = perx / NBX;
  int ms = j / (4 * NBX), nb = (j >> 2) % NBX, mq = j & 3;
  const long m0 = (long)(xcd * mpx + ms * 4 + mq) * 256;
  const long n0 = (long)nb * 256;
  const unsigned short* bt = BSEL ? (Bt + (m0 >> 12) * 1048576) : Bt;
  const float* biasp = BBIAS ? (bias + (m0 >> 12) * 1024) : bias;

  const int NT = K >> 6, NI = NT >> 1;   // NT even for all our shapes

  const int lr = lane & 15, lc = (lane >> 4) * 16;
  const int eA = lc ^ ((lr & 7) << 4);
  const char* paK0 = smb + wm * 8192 + lr * 128 + eA;
  const char* paK1 = smb + wm * 8192 + lr * 128 + (eA ^ 64);
  const char* pbK0 = smb + 65536 + wn * 4096 + lr * 128 + eA;
  const char* pbK1 = smb + 65536 + wn * 4096 + lr * 128 + (eA ^ 64);

  short8 afr0[4][2], afr1[4][2];
  short8 bfr0[2][2], bfr1[2][2];
  f32x4 acc[8][4] = {};

  auto stA = [&](int buf, int ph, int kt) {
#pragma unroll
    for (int rnd = 0; rnd < 2; ++rnd) {
      int o = rnd * 8192 + tid * 16;
      int wms = o >> 13, rsw = (o >> 7) & 63, cb = o & 127;
      int pcb = cb ^ ((rsw & 7) << 4);
      const unsigned short* src = A + (m0 + wms * 128 + ph * 64 + rsw) * (long)lda + kt * 64 + (pcb >> 1);
      gload16(src, (unsigned short*)(smb + buf * 32768 + ph * 16384 + o));
    }
  };
  auto stB = [&](int buf, int ph, int kt) {
#pragma unroll
    for (int rnd = 0; rnd < 2; ++rnd) {
      int o = rnd * 8192 + tid * 16;
      int wns = (o >> 12) & 3, rsw = (o >> 7) & 31, cb = o & 127;
      int pcb = cb ^ ((rsw & 7) << 4);
      const unsigned short* src = bt + (n0 + wns * 64 + ph * 32 + rsw) * (long)ldb + kt * 64 + (pcb >> 1);
      gload16(src, (unsigned short*)(smb + 65536 + buf * 32768 + ph * 16384 + o));
    }
  };

  stA(0, 0, 0); stA(0, 1, 0); stB(0, 0, 0); stB(0, 1, 0);
  stA(1, 0, 1); stA(1, 1, 1); stB(1, 0, 1); stB(1, 1, 1);
  VMW(8);
  BARR;
  rdA2(afr0, paK0, paK1, 0);
  rdB2(bfr0, pbK0, pbK1, 0);

  for (int i = 0; i < NI; ++i) {
    int t2 = 2 * i + 2, t3 = 2 * i + 3;
    bool more = t2 < NT;
    // ---- tile 2i (buf0) ----
    LBARR;
    rdB2(bfr1, pbK0, pbK1, 16384);
    mfmaq_f<0>(afr0, bfr0, &acc[0]);
    LBARR;
    rdA2(afr1, paK0, paK1, 16384);
    mfmaq_f<1>(afr0, bfr1, &acc[0]);
    LBARR;
    if (more) { stA(0, 0, t2); stA(0, 1, t2); }
    mfmaq_f<0>(afr1, bfr0, &acc[4]);
    if (more) { VMW(4); } else { VMW(0); }
    LBARR;
    rdA2(afr0, paK0, paK1, 32768);
    rdB2(bfr0, pbK0, pbK1, 32768);
    if (more) { stB(0, 0, t2); stB(0, 1, t2); }
    mfmaq_f<1>(afr1, bfr1, &acc[4]);
    // ---- tile 2i+1 (buf1) ----
    LBARR;
    rdB2(bfr1, pbK0, pbK1, 32768 + 16384);
    mfmaq_f<0>(afr0, bfr0, &acc[0]);
    LBARR;
    rdA2(afr1, paK0, paK1, 32768 + 16384);
    mfmaq_f<1>(afr0, bfr1, &acc[0]);
    LBARR;
    if (more) { stA(1, 0, t3); stA(1, 1, t3); }
    mfmaq_f<0>(afr1, bfr0, &acc[4]);
    if (more) { VMW(4); } else { VMW(0); }
    LBARR;
    if (more) { rdA2(afr0, paK0, paK1, 0); rdB2(bfr0, pbK0, pbK1, 0); }
    if (more) { stB(1, 0, t3); stB(1, 1, t3); }
    mfmaq_f<1>(afr1, bfr1, &acc[4]);
  }

  // Epilogue. EPI7 accumulates per-row sum-of-squares into ssb.
#pragma unroll
  for (int f = 0; f < 8; ++f) {
    float ssp[4] = {0.0f, 0.0f, 0.0f, 0.0f};
#pragma unroll
    for (int g = 0; g < 4; ++g) {
      long col = n0 + wn * 64 + g * 16 + (lane & 15);
      float bv = (EPI == 6) ? 0.0f : biasp[col];
      if (EPI == 7) bv += aux[col];              // aux = bo
      float gv = (EPI == 5) ? aux[col] : 0.0f;   // aux = g1
#pragma unroll
      for (int r = 0; r < 4; ++r) {
        long row = m0 + wm * 128 + f * 16 + (lane >> 4) * 4 + r;
        float o = acc[f][g][r] + bv;
        if (EPI == 7) o += b2f(residb[row * (long)ldr + col]);
        if (EPI == 5) {
          float rsv = rsqrtf(ssb[row] * (1.0f / 1024.0f) + 1e-6f);
          o += b2f(residb[row * (long)ldr + col]) * rsv * gv;
        }
        if (EPI == 7) ssp[r] += o * o;
        C[row * (long)ldc + col] = f2b(o);
      }
    }
    if (EPI == 7) {
#pragma unroll
      for (int r = 0; r < 4; ++r) {
        float p = ssp[r];
        p += __shfl_xor(p, 1, 64);
        p += __shfl_xor(p, 2, 64);
        p += __shfl_xor(p, 4, 64);
        p += __shfl_xor(p, 8, 64);
        if ((lane & 15) == 0) {
          long row = m0 + wm * 128 + f * 16 + (lane >> 4) * 4 + r;
          atomicAdd(&ssb[row], p);
        }
      }
    }
  }
}

// ---------------------------------------------------------------------------
// m97-structure 128^2 GEMM (2 blocks/CU). EPI 4: tanh(rs(ssb[row])*acc+bias);
// EPI 5: no bias (plain C = A@Bt^T).
// ---------------------------------------------------------------------------
template <int EPI>
__global__ __launch_bounds__(256, 2) void gemm_bt(
    const unsigned short* __restrict__ A, int lda,
    const unsigned short* __restrict__ Bt, int ldb,
    unsigned short* __restrict__ C, int ldc,
    const float* __restrict__ bias, const float* __restrict__ ssb, int K) {
  __shared__ __align__(16) unsigned short Asm[128 * 32];
  __shared__ __align__(16) unsigned short Bsm[128 * 32];
  const int tid = threadIdx.x;
  const int lane = tid & 63, wid = tid >> 6;
  const int wr = wid >> 1, wc = wid & 1;
  const long m0 = (long)blockIdx.y * 128;
  const long n0 = (long)blockIdx.x * 128;

  f32x4 acc[4][4] = {};

  for (int kk = 0; kk < K; kk += 32) {
    __syncthreads();
#pragma unroll
    for (int i = 0; i < 2; ++i) {
      int slot = i * 256 + tid;
      int r = slot >> 2, cg = (slot & 3) * 8;
      gload16(A + (m0 + r) * (long)lda + kk + cg, &Asm[slot * 8]);
      gload16(Bt + (n0 + r) * (long)ldb + kk + cg, &Bsm[slot * 8]);
    }
    __syncthreads();
    short8 af[4], bfr[4];
#pragma unroll
    for (int mt = 0; mt < 4; ++mt)
      af[mt] = *(const short8*)&Asm[(wr * 64 + mt * 16 + (lane & 15)) * 32 + (lane >> 4) * 8];
#pragma unroll
    for (int nt = 0; nt < 4; ++nt)
      bfr[nt] = *(const short8*)&Bsm[(wc * 64 + nt * 16 + (lane & 15)) * 32 + (lane >> 4) * 8];
#pragma unroll
    for (int mt = 0; mt < 4; ++mt)
#pragma unroll
      for (int nt = 0; nt < 4; ++nt)
        acc[mt][nt] = __builtin_amdgcn_mfma_f32_16x16x32_bf16(af[mt], bfr[nt], acc[mt][nt], 0, 0, 0);
  }

  const long row0 = m0 + wr * 64 + ((lane >> 4) * 4);
  const long col0 = n0 + wc * 64 + (lane & 15);
#pragma unroll
  for (int mt = 0; mt < 4; ++mt) {
#pragma unroll
    for (int nt = 0; nt < 4; ++nt) {
      long col = col0 + nt * 16;
      float bv = (EPI == 5) ? 0.0f : bias[col];
      f32x4 v = acc[mt][nt];
#pragma unroll
      for (int r = 0; r < 4; ++r) {
        long row = row0 + mt * 16 + r;
        float o = v[r];
        if (EPI == 4) {
          float rsv = rsqrtf(ssb[row] * (1.0f / 1024.0f) + 1e-6f);
          o = tanhf(o * rsv + bv);
        } else o += bv;
        C[row * (long)ldc + col] = f2b(o);
      }
    }
  }
}

// ---------------------------------------------------------------------------
// scores via MFMA (verified rounds 5-15); QK buffer stride 2048.
// ---------------------------------------------------------------------------
__device__ __forceinline__ int sperm(int e) { return ((e + (e >> 3)) & 7) << 4; }

__global__ __launch_bounds__(256) void scores_mfma(
    const unsigned short* __restrict__ QK, float* __restrict__ part) {
  __shared__ __align__(16) char lds[32768];
  int bh = blockIdx.x, seg = blockIdx.y;
  int b = bh >> 4, h = bh & 15;
  int tid = threadIdx.x, lane = tid & 63, wid = tid >> 6;
  int e0 = (tid & 7) * 8;
  int sl0 = (tid >> 3) * 4;
  const unsigned short* Qg = QK + h * 64;
  const unsigned short* Kg = QK + 1024 + h * 64;
  f32x4 acc[4] = {};

  for (int ch = 0; ch < 8; ++ch) {
    long S0 = (long)b * 4096 + seg * 1024 + ch * 128;
    __syncthreads();
    short8 kv0 = *(const short8*)(Kg + (S0 + sl0 + 0) * 2048 + e0);
    short8 kv1 = *(const short8*)(Kg + (S0 + sl0 + 1) * 2048 + e0);
    short8 kv2 = *(const short8*)(Kg + (S0 + sl0 + 2) * 2048 + e0);
    short8 kv3 = *(const short8*)(Kg + (S0 + sl0 + 3) * 2048 + e0);
    short8 qv0 = *(const short8*)(Qg + (S0 + sl0 + 0) * 2048 + e0);
    short8 qv1 = *(const short8*)(Qg + (S0 + sl0 + 1) * 2048 + e0);
    short8 qv2 = *(const short8*)(Qg + (S0 + sl0 + 2) * 2048 + e0);
    short8 qv3 = *(const short8*)(Qg + (S0 + sl0 + 3) * 2048 + e0);
#pragma unroll
    for (int je = 0; je < 8; ++je) {
      int e = e0 + je;
      int sw = sperm(e);
      char* rowK = lds + e * 256;
      char* rowQ = lds + 16384 + e * 256;
      unsigned int klo = (unsigned short)kv0[je] | ((unsigned int)(unsigned short)kv1[je] << 16);
      unsigned int khi = (unsigned short)kv2[je] | ((unsigned int)(unsigned short)kv3[je] << 16);
      unsigned int qlo = (unsigned short)qv0[je] | ((unsigned int)(unsigned short)qv1[je] << 16);
      unsigned int qhi = (unsigned short)qv2[je] | ((unsigned int)(unsigned short)qv3[je] << 16);
      *(unsigned int*)(rowK + ((sl0 * 2) ^ sw)) = klo;
      *(unsigned int*)(rowK + ((sl0 * 2 + 4) ^ sw)) = khi;
      *(unsigned int*)(rowQ + ((sl0 * 2) ^ sw)) = qlo;
      *(unsigned int*)(rowQ + ((sl0 * 2 + 4) ^ sw)) = qhi;
    }
    __syncthreads();
#pragma unroll
    for (int ksi = 0; ksi < 4; ++ksi) {
      int colb = ksi * 64 + (lane >> 4) * 16;
      int erA = wid * 16 + (lane & 15);
      short8 af = *(const short8*)(lds + erA * 256 + (colb ^ sperm(erA)));
#pragma unroll
      for (int n = 0; n < 4; ++n) {
        int erB = n * 16 + (lane & 15);
        short8 bf = *(const short8*)(lds + 16384 + erB * 256 + (colb ^ sperm(erB)));
        acc[n] = __builtin_amdgcn_mfma_f32_16x16x32_bf16(af, bf, acc[n], 0, 0, 0);
      }
    }
  }
  float* dst = part + ((long)bh * 4 + seg) * 4096;
#pragma unroll
  for (int n = 0; n < 4; ++n)
#pragma unroll
    for (int r = 0; r < 4; ++r) {
      int k = wid * 16 + (lane >> 4) * 4 + r;
      int q = n * 16 + (lane & 15);
      dst[k * 64 + q] = acc[n][r];
    }
}

// softmax over k (per q column), scores/8; writes w row-major: Wb[bh][k][q]
__global__ __launch_bounds__(64) void softmax_Wb(
    const float* __restrict__ part, const int* __restrict__ mask,
    unsigned short* __restrict__ Wb) {
  __shared__ float lt[64][65];
  int bh = blockIdx.x, q = threadIdx.x;
  int b = bh >> 4;
  const float* p0 = part + (long)bh * 4 * 4096;
  float s[64];
#pragma unroll
  for (int k = 0; k < 64; ++k)
    s[k] = p0[k * 64 + q] + p0[4096 + k * 64 + q] + p0[8192 + k * 64 + q] + p0[12288 + k * 64 + q];
  bool live = (mask[b * 64 + q] != 0);
  float m = -1e30f;
#pragma unroll
  for (int k = 0; k < 64; ++k) m = fmaxf(m, s[k]);
  float sum = 0.0f;
#pragma unroll
  for (int k = 0; k < 64; ++k) {
    s[k] = __expf((s[k] - m) * 0.125f);
    sum += s[k];
  }
  float inv = live ? 1.0f / sum : 0.0f;
#pragma unroll
  for (int k = 0; k < 64; ++k) lt[k][q] = s[k] * inv;
  __syncthreads();
  unsigned short* o = Wb + (long)bh * 4096 + q * 64;
#pragma unroll
  for (int j8 = 0; j8 < 8; ++j8) {
    short8 ov;
#pragma unroll
    for (int j = 0; j < 8; ++j) ov[j] = (short)f2b(lt[q][j8 * 8 + j]);
    *(short8*)(o + j8 * 8) = ov;
  }
}

// WPT[b][d][h*64+k] = sum_q Wo[h*64+q][d] * w_bh[k][q]
// Fused: atomicAdd partial of hb[b][d] = sum_col WPT[d][col]*bv[col].
__global__ __launch_bounds__(256) void wpt_kernel(
    const unsigned short* __restrict__ WoT, const unsigned short* __restrict__ Wb,
    unsigned short* __restrict__ WPT, const float* __restrict__ bv,
    float* __restrict__ hb) {
  int dblk = blockIdx.x;   // 4
  int h = blockIdx.y;      // 16
  int b = blockIdx.z;      // 8
  int tid = threadIdx.x, lane = tid & 63, wid = tid >> 6;
  int d0 = dblk * 256 + wid * 64;
  const unsigned short* wb = Wb + (long)(b * 16 + h) * 4096;
  f32x4 acc[4][4] = {};
#pragma unroll
  for (int ks = 0; ks < 2; ++ks) {
    short8 bf[4];
#pragma unroll
    for (int nt = 0; nt < 4; ++nt)
      bf[nt] = *(const short8*)(wb + (nt * 16 + (lane & 15)) * 64 + ks * 32 + (lane >> 4) * 8);
#pragma unroll
    for (int mt = 0; mt < 4; ++mt) {
      short8 af = *(const short8*)(WoT + (long)(d0 + mt * 16 + (lane & 15)) * 1024 + h * 64 + ks * 32 + (lane >> 4) * 8);
#pragma unroll
      for (int nt = 0; nt < 4; ++nt)
        acc[mt][nt] = __builtin_amdgcn_mfma_f32_16x16x32_bf16(af, bf[nt], acc[mt][nt], 0, 0, 0);
    }
  }
  float bvv[4];
#pragma unroll
  for (int nt = 0; nt < 4; ++nt) bvv[nt] = bv[h * 64 + nt * 16 + (lane & 15)];
#pragma unroll
  for (int mt = 0; mt < 4; ++mt) {
#pragma unroll
    for (int r = 0; r < 4; ++r) {
      long row = d0 + mt * 16 + (lane >> 4) * 4 + r;
      float p = 0.0f;
#pragma unroll
      for (int nt = 0; nt < 4; ++nt) {
        float o = acc[mt][nt][r];
        WPT[(long)b * 1048576 + row * 1024 + h * 64 + nt * 16 + (lane & 15)] = f2b(o);
        p += o * bvv[nt];
      }
      p += __shfl_xor(p, 1, 64);
      p += __shfl_xor(p, 2, 64);
      p += __shfl_xor(p, 4, 64);
      p += __shfl_xor(p, 8, 64);
      if ((lane & 15) == 0) atomicAdd(&hb[b * 1024 + row], p);
    }
  }
}

// rmsnorm over D=1024; one block per row. bf16 in; f32 out.
__global__ __launch_bounds__(256) void rmsnorm_k(
    const unsigned short* __restrict__ in, const float* __restrict__ g,
    float* __restrict__ outf) {
  long row = blockIdx.x;
  int tid = threadIdx.x;
  short4v u = *(const short4v*)(in + row * 1024 + tid * 4);
  float v[4];
  float ss = 0.0f;
#pragma unroll
  for (int i = 0; i < 4; ++i) {
    v[i] = b2f((unsigned short)u[i]);
    ss += v[i] * v[i];
  }
#pragma unroll
  for (int off = 32; off > 0; off >>= 1) ss += __shfl_xor(ss, off, 64);
  __shared__ float wsum[4];
  if ((tid & 63) == 0) wsum[tid >> 6] = ss;
  __syncthreads();
  float tot = wsum[0] + wsum[1] + wsum[2] + wsum[3];
  float rsv = rsqrtf(tot * (1.0f / 1024.0f) + 1e-6f);
  f32x4 gv = *(const f32x4*)(g + tid * 4);
  f32x4 ov;
#pragma unroll
  for (int i = 0; i < 4; ++i) ov[i] = v[i] * rsv * gv[i];
  *(f32x4*)(outf + row * 1024 + tid * 4) = ov;
}

// ---------------------------------------------------------------------------
extern "C" void kernel_launch(void* const* d_in, const int* in_sizes, int n_in,
                              void* d_out, int out_size, void* d_ws, size_t ws_size,
                              hipStream_t stream) {
  const float* x  = (const float*)d_in[0];
  const int* mask = (const int*)d_in[1];
  const float* Wq = (const float*)d_in[2];
  const float* bq = (const float*)d_in[3];
  const float* Wk = (const float*)d_in[4];
  const float* bk = (const float*)d_in[5];
  const float* Wv = (const float*)d_in[6];
  const float* bv = (const float*)d_in[7];
  const float* Wo = (const float*)d_in[8];
  const float* bo = (const float*)d_in[9];
  const float* W1 = (const float*)d_in[10];
  const float* b1 = (const float*)d_in[11];
  const float* W2 = (const float*)d_in[12];
  const float* b2 = (const float*)d_in[13];
  const float* g1 = (const float*)d_in[14];
  const float* g2 = (const float*)d_in[15];

  char* ws = (char*)d_ws;
  size_t off = 0;
  auto alc = [&](size_t n) { size_t o = off; off += (n + 255) & ~(size_t)255; return o; };
  unsigned short* BqkT  = (unsigned short*)(ws + alc(2048UL * 1024 * 2));
  unsigned short* WoT   = (unsigned short*)(ws + alc(1024UL * 1024 * 2));
  unsigned short* W1T   = (unsigned short*)(ws + alc(128UL * 1024 * 2));    // g1-folded
  unsigned short* W2T   = (unsigned short*)(ws + alc(1024UL * 128 * 2));
  unsigned short* WvR   = (unsigned short*)(ws + alc(1024UL * 1024 * 2));
  float*          bqkv  = (float*)(ws + alc(3072UL * 4));
  float*          HBb   = (float*)(ws + alc(8192UL * 4));
  unsigned short* R0    = (unsigned short*)(ws + alc(32768UL * 1024 * 2));  // xb -> hf
  unsigned short* R1    = (unsigned short*)(ws + alc(32768UL * 2048 * 2));  // QK
  unsigned short* R2    = (unsigned short*)(ws + alc(32768UL * 1024 * 2));  // h1
  unsigned short* WPb   = (unsigned short*)(ws + alc(8UL * 1048576 * 2));   // WPT
  unsigned short* WVPb  = (unsigned short*)(ws + alc(8UL * 1048576 * 2));   // WVP
  unsigned short* Tb    = (unsigned short*)(ws + alc(32768UL * 128 * 2));
  float*          SP    = (float*)(ws + alc(512UL * 4096 * 4));
  unsigned short* Wbuf  = (unsigned short*)(ws + alc(128UL * 4096 * 2));
  float*          SSb   = (float*)(ws + alc(32768UL * 4));
  if (ws_size < off) return;

  // Dataflow (C always disjoint from A/B/resid):
  //   prep:   x -> xb(R0); weights; bqkv; zero HBb/SSb
  //   QK:     xb(R0) @ BqkT -> QK(R1)                 [gemm8p EPI0]
  //   scores: QK(R1) -> SP ; softmax -> Wbuf
  //   wpt:    -> WPT(WPb) + atomics hb(HBb)
  //   WVP:    WPT @ WvR -> WVP(WVPb)                  [gemm_bt EPI5, full GPU]
  //   h1:     xb @ WVP_b + hb_b + bo + xb -> h1(R2)   [gemm8p EPI7; SS -> SSb]
  //   FF1:    h1 @ W1g, tanh(rs(SSb)*acc+b1) -> t(Tb) [gemm_bt EPI4]
  //   FF2:    t @ W2T + b2 + h1*rs(SSb)*g1 -> hf(R0)  [gemm8p EPI5; xb dead]
  //   rms2:   hf(R0) -> out
  unsigned short* xb   = R0;
  unsigned short* HFb  = R0;
  unsigned short* QKb  = R1;
  unsigned short* H1b  = R2;
  float* outp = (float*)d_out;

  prep_kernel<<<17475, 256, 0, stream>>>(x, xb, Wq, Wk, Wv, Wo, W1, W2, bq, bk, bv, g1,
                                         BqkT, WoT, W1T, W2T, WvR, bqkv, HBb, SSb);
  // QK = xb @ [Wq|Wk]^T + b  (N=2048; grid 128x8 = 1024)
  gemm8p<0, 0, 0><<<1024, 512, 131072, stream>>>(xb, 1024, BqkT, 1024, QKb, 2048,
                                                 bqkv, nullptr, 0, nullptr, nullptr,
                                                 1024, 8);
  scores_mfma<<<dim3(128, 4), 256, 0, stream>>>(QKb, SP);
  softmax_Wb<<<128, 64, 0, stream>>>(SP, mask, Wbuf);
  wpt_kernel<<<dim3(4, 16, 8), 256, 0, stream>>>(WoT, Wbuf, WPb, bqkv + 2048, HBb);
  // WVP = WPT_stacked @ WvR^T  (plain M=8192 GEMM; grid (8,64)=512, 2/CU)
  gemm_bt<5><<<dim3(8, 64), 256, 0, stream>>>(WPb, 1024, WvR, 1024, WVPb, 1024,
                                              nullptr, nullptr, 1024);
  // h1 = xb + xb @ WVP_b^T + hb_b + bo ; SS atomics into SSb
  gemm8p<7, 1, 1><<<512, 512, 131072, stream>>>(xb, 1024, WVPb, 1024, H1b, 1024,
                                                HBb, xb, 1024, SSb, bo,
                                                1024, 4);
  // t = tanh(rs * (h1 @ W1g^T) + b1)
  gemm_bt<4><<<dim3(1, 256), 256, 0, stream>>>(H1b, 1024, W1T, 1024, Tb, 128, b1, SSb, 1024);
  // hf = t@W2T + b2 + h1*rs*g1
  gemm8p<5, 0, 0><<<512, 512, 131072, stream>>>(Tb, 128, W2T, 128, HFb, 1024,
                                                b2, H1b, 1024, SSb, g1,
                                                128, 4);
  rmsnorm_k<<<32768, 256, 0, stream>>>(HFb, g2, outp);
}

// Round 17
// 446.620 us; speedup vs baseline: 1.0717x; 1.0012x over previous
//
#include <hip/hip_runtime.h>
#include <math.h>

typedef __attribute__((ext_vector_type(4))) float f32x4;
typedef __attribute__((ext_vector_type(8))) short short8;   // 8 bf16 raw bits
typedef __attribute__((ext_vector_type(4))) short short4v;  // 4 bf16 raw bits

__device__ __forceinline__ float b2f(unsigned short u) {
  unsigned int x = ((unsigned int)u) << 16;
  return __builtin_bit_cast(float, x);
}
__device__ __forceinline__ unsigned short f2b(float f) {
  unsigned int x = __builtin_bit_cast(unsigned int, f);
  x += 0x7fffu + ((x >> 16) & 1u);   // round-to-nearest-even
  return (unsigned short)(x >> 16);
}

// async global->LDS, 16B per lane. LDS dest must be lane-contiguous (wave base + lane*16).
__device__ __forceinline__ void gload16(const unsigned short* g, unsigned short* l) {
  __builtin_amdgcn_global_load_lds(
      (__attribute__((address_space(1))) void*)(unsigned long long)(const void*)g,
      (__attribute__((address_space(3))) void*)l, 16, 0, 0);
}

#define BARR  { __builtin_amdgcn_sched_barrier(0); __builtin_amdgcn_s_barrier(); __builtin_amdgcn_sched_barrier(0); }
#define LBARR { __builtin_amdgcn_sched_barrier(0); asm volatile("s_waitcnt lgkmcnt(0)" ::: "memory"); __builtin_amdgcn_s_barrier(); __builtin_amdgcn_sched_barrier(0); }
// CROSS-WAVE RULE: vmcnt gate protecting a cooperatively-staged LDS buffer sits
// BEFORE the barrier preceding the reads. BUFFER RULE: a GEMM's C region must
// be disjoint from its A, B, and residual regions. REGISTER RULE (round 11):
// unified VGPR/AGPR file — acc[8][4]=128 regs/wave -> 2 waves/SIMD cap.
// LDS-BW RULE (round 14): fragment re-reads cap MfmaUtil at ~41%. OCCUPANCY
// RULE (round 16): pick the GEMM variant whose grid fills all 256 CUs.
// IDENTITY-FOLD (round 17): h1's x-residual folded into WVP's diagonal.
#define VMW(n) { __builtin_amdgcn_sched_barrier(0); asm volatile("s_waitcnt vmcnt(" #n ")" ::: "memory"); __builtin_amdgcn_sched_barrier(0); }

// ---------------------------------------------------------------------------
// prep_kernel: x->bf16 + weight repacks + bias concat + HBb/SSb zeroing.
// ---------------------------------------------------------------------------
__global__ __launch_bounds__(256) void prep_kernel(
    const float* __restrict__ x, unsigned short* __restrict__ xb,
    const float* __restrict__ Wq, const float* __restrict__ Wk,
    const float* __restrict__ Wv, const float* __restrict__ Wo,
    const float* __restrict__ W1, const float* __restrict__ W2,
    const float* __restrict__ bq, const float* __restrict__ bk, const float* __restrict__ bv,
    const float* __restrict__ g1,
    unsigned short* __restrict__ BqkT, unsigned short* __restrict__ WoT,
    unsigned short* __restrict__ W1T, unsigned short* __restrict__ W2T,
    unsigned short* __restrict__ WvR,
    float* __restrict__ bqkv,
    float* __restrict__ HBz, float* __restrict__ SSz) {
  __shared__ float tile[64][65];
  int nb = blockIdx.x, t = threadIdx.x;
  if (nb < 16384) {
    long i = (long)nb * 256 + t;
    f32x4 a = ((const f32x4*)x)[i * 2];
    f32x4 b = ((const f32x4*)x)[i * 2 + 1];
    short8 o;
#pragma unroll
    for (int j = 0; j < 4; ++j) { o[j] = (short)f2b(a[j]); o[4 + j] = (short)f2b(b[j]); }
    ((short8*)xb)[i] = o;
    return;
  }
  int n0 = nb - 16384;
  if (n0 == 1088) {
#pragma unroll
    for (int it = 0; it < 12; ++it) {
      int idx = it * 256 + t;
      float v = (idx < 1024) ? bq[idx] : (idx < 2048 ? bk[idx - 1024] : bv[idx - 2048]);
      bqkv[idx] = v;
    }
    return;
  }
  if (n0 == 1089) {                       // zero HBb (8192 f32)
#pragma unroll
    for (int it = 0; it < 32; ++it) HBz[it * 256 + t] = 0.0f;
    return;
  }
  if (n0 == 1090) {                       // zero SSb (32768 f32)
#pragma unroll
    for (int it = 0; it < 128; ++it) SSz[it * 256 + t] = 0.0f;
    return;
  }
  if (n0 >= 832) {                        // WvR[d][h*64+e] = Wv[h][d][e] (copy+cvt)
    int rem = n0 - 832, h = rem >> 4, dc = rem & 15;
    int r = t >> 2, c0 = (t & 3) * 16;
    const float* s = Wv + ((long)h * 1024 + dc * 64 + r) * 64 + c0;
    unsigned short* d = WvR + (long)(dc * 64 + r) * 1024 + h * 64 + c0;
#pragma unroll
    for (int j4 = 0; j4 < 4; ++j4) {
      f32x4 v = *(const f32x4*)(s + j4 * 4);
      short4v o;
#pragma unroll
      for (int j = 0; j < 4; ++j) o[j] = (short)f2b(v[j]);
      *(short4v*)(d + j4 * 4) = o;
    }
    return;
  }
  const float* src; unsigned short* dst; int sld, dld;
  bool foldg = false; int dbase = 0;
  if (n0 < 512) {                         // Wq/Wk -> BqkT rows [w*1024 + h*64 + e]
    int w = n0 >> 8, rem = n0 & 255, h = rem >> 4, dc = rem & 15;
    const float* W = (w == 0) ? Wq : Wk;
    src = W + ((long)h * 1024 + dc * 64) * 64;                 sld = 64;
    dst = BqkT + (long)(w * 1024 + h * 64) * 1024 + dc * 64;   dld = 1024;
  } else if (n0 < 768) {
    int rem = n0 - 512, dr = rem >> 4, jc = rem & 15;
    src = Wo + (long)dr * 64 * 1024 + jc * 64;                 sld = 1024;
    dst = WoT + (long)jc * 64 * 1024 + dr * 64;                dld = 1024;
  } else if (n0 < 800) {
    int rem = n0 - 768, dr = rem >> 1, fc = rem & 1;
    src = W1 + (long)dr * 64 * 128 + fc * 64;                  sld = 128;
    dst = W1T + (long)fc * 64 * 1024 + dr * 64;                dld = 1024;
    foldg = true; dbase = dr * 64;
  } else {
    int rem = n0 - 800, fr = rem >> 4, jc = rem & 15;
    src = W2 + (long)fr * 64 * 1024 + jc * 64;                 sld = 1024;
    dst = W2T + (long)jc * 64 * 128 + fr * 64;                 dld = 128;
  }
  int r = t >> 2, c0 = (t & 3) * 16;
#pragma unroll
  for (int j4 = 0; j4 < 4; ++j4) {
    f32x4 v = *(const f32x4*)(src + (long)r * sld + c0 + j4 * 4);
    tile[c0 + j4 * 4 + 0][r] = v[0];
    tile[c0 + j4 * 4 + 1][r] = v[1];
    tile[c0 + j4 * 4 + 2][r] = v[2];
    tile[c0 + j4 * 4 + 3][r] = v[3];
  }
  __syncthreads();
  short8 o0, o1;
#pragma unroll
  for (int j = 0; j < 8; ++j) {
    float v0 = tile[r][c0 + j], v1 = tile[r][c0 + 8 + j];
    if (foldg) { v0 *= g1[dbase + c0 + j]; v1 *= g1[dbase + c0 + 8 + j]; }
    o0[j] = (short)f2b(v0);
    o1[j] = (short)f2b(v1);
  }
  *(short8*)(dst + (long)r * dld + c0) = o0;
  *(short8*)(dst + (long)r * dld + c0 + 8) = o1;
}

// ---------------------------------------------------------------------------
// 256x256 bf16 GEMM v2.3 (verified rounds 10/12/13/15/16).
// EPI: 0 = +bias ; 5 = +bias + h1*rs*g1 resid ; 6 = no bias ;
//      7 = +bias(pb) + bias2 + bf16 resid + row-SS atomics ;
//      8 = +bias(pb) + bias2 + row-SS atomics (NO resid; identity in B).
// BSEL: per-batch B (+(m0>>12)*1M). BBIAS: per-batch bias.
// ---------------------------------------------------------------------------
__device__ __forceinline__ void rdA2(short8 (&dst)[4][2], const char* paK0,
                                     const char* paK1, int off) {
#pragma unroll
  for (int fr = 0; fr < 4; ++fr) {
    dst[fr][0] = *(const short8*)(paK0 + off + fr * 2048);
    dst[fr][1] = *(const short8*)(paK1 + off + fr * 2048);
  }
}
__device__ __forceinline__ void rdB2(short8 (&dst)[2][2], const char* pbK0,
                                     const char* pbK1, int off) {
#pragma unroll
  for (int gr = 0; gr < 2; ++gr) {
    dst[gr][0] = *(const short8*)(pbK0 + off + gr * 2048);
    dst[gr][1] = *(const short8*)(pbK1 + off + gr * 2048);
  }
}
template <int BPH>
__device__ __forceinline__ void mfmaq_f(const short8 (&afr)[4][2], const short8 (&bf)[2][2],
                                        f32x4 (*ac)[4]) {
  __builtin_amdgcn_s_setprio(1);
#pragma unroll
  for (int fi = 0; fi < 4; ++fi)
#pragma unroll
    for (int gj = 0; gj < 2; ++gj)
#pragma unroll
      for (int ks = 0; ks < 2; ++ks)
        ac[fi][BPH * 2 + gj] = __builtin_amdgcn_mfma_f32_16x16x32_bf16(
            afr[fi][ks], bf[gj][ks], ac[fi][BPH * 2 + gj], 0, 0, 0);
  __builtin_amdgcn_s_setprio(0);
}

template <int EPI, int BSEL, int BBIAS>
__global__ __launch_bounds__(512, 2) void gemm8p(
    const unsigned short* __restrict__ A, int lda,
    const unsigned short* __restrict__ Bt, int ldb,
    unsigned short* __restrict__ C, int ldc,
    const float* __restrict__ bias,
    const unsigned short* __restrict__ residb, int ldr,
    float* __restrict__ ssb, const float* __restrict__ aux,
    int K, int NBX) {
  extern __shared__ char smb[];
  const int tid = threadIdx.x;
  const int lane = tid & 63, wid = tid >> 6;
  const int wm = wid >> 2, wn = wid & 3;

  int orig = blockIdx.x;
  int xcd = orig & 7, j = orig >> 3;
  int perx = gridDim.x >> 3;
  int mpx = perx / NBX;
  int ms = j / (4 * NBX), nb = (j >> 2) % NBX, mq = j & 3;
  const long m0 = (long)(xcd * mpx + ms * 4 + mq) * 256;
  const long n0 = (long)nb * 256;
  const unsigned short* bt = BSEL ? (Bt + (m0 >> 12) * 1048576) : Bt;
  const float* biasp = BBIAS ? (bias + (m0 >> 12) * 1024) : bias;

  const int NT = K >> 6, NI = NT >> 1;   // NT even for all our shapes

  const int lr = lane & 15, lc = (lane >> 4) * 16;
  const int eA = lc ^ ((lr & 7) << 4);
  const char* paK0 = smb + wm * 8192 + lr * 128 + eA;
  const char* paK1 = smb + wm * 8192 + lr * 128 + (eA ^ 64);
  const char* pbK0 = smb + 65536 + wn * 4096 + lr * 128 + eA;
  const char* pbK1 = smb + 65536 + wn * 4096 + lr * 128 + (eA ^ 64);

  short8 afr0[4][2], afr1[4][2];
  short8 bfr0[2][2], bfr1[2][2];
  f32x4 acc[8][4] = {};

  auto stA = [&](int buf, int ph, int kt) {
#pragma unroll
    for (int rnd = 0; rnd < 2; ++rnd) {
      int o = rnd * 8192 + tid * 16;
      int wms = o >> 13, rsw = (o >> 7) & 63, cb = o & 127;
      int pcb = cb ^ ((rsw & 7) << 4);
      const unsigned short* src = A + (m0 + wms * 128 + ph * 64 + rsw) * (long)lda + kt * 64 + (pcb >> 1);
      gload16(src, (unsigned short*)(smb + buf * 32768 + ph * 16384 + o));
    }
  };
  auto stB = [&](int buf, int ph, int kt) {
#pragma unroll
    for (int rnd = 0; rnd < 2; ++rnd) {
      int o = rnd * 8192 + tid * 16;
      int wns = (o >> 12) & 3, rsw = (o >> 7) & 31, cb = o & 127;
      int pcb = cb ^ ((rsw & 7) << 4);
      const unsigned short* src = bt + (n0 + wns * 64 + ph * 32 + rsw) * (long)ldb + kt * 64 + (pcb >> 1);
      gload16(src, (unsigned short*)(smb + 65536 + buf * 32768 + ph * 16384 + o));
    }
  };

  stA(0, 0, 0); stA(0, 1, 0); stB(0, 0, 0); stB(0, 1, 0);
  stA(1, 0, 1); stA(1, 1, 1); stB(1, 0, 1); stB(1, 1, 1);
  VMW(8);
  BARR;
  rdA2(afr0, paK0, paK1, 0);
  rdB2(bfr0, pbK0, pbK1, 0);

  for (int i = 0; i < NI; ++i) {
    int t2 = 2 * i + 2, t3 = 2 * i + 3;
    bool more = t2 < NT;
    // ---- tile 2i (buf0) ----
    LBARR;
    rdB2(bfr1, pbK0, pbK1, 16384);
    mfmaq_f<0>(afr0, bfr0, &acc[0]);
    LBARR;
    rdA2(afr1, paK0, paK1, 16384);
    mfmaq_f<1>(afr0, bfr1, &acc[0]);
    LBARR;
    if (more) { stA(0, 0, t2); stA(0, 1, t2); }
    mfmaq_f<0>(afr1, bfr0, &acc[4]);
    if (more) { VMW(4); } else { VMW(0); }
    LBARR;
    rdA2(afr0, paK0, paK1, 32768);
    rdB2(bfr0, pbK0, pbK1, 32768);
    if (more) { stB(0, 0, t2); stB(0, 1, t2); }
    mfmaq_f<1>(afr1, bfr1, &acc[4]);
    // ---- tile 2i+1 (buf1) ----
    LBARR;
    rdB2(bfr1, pbK0, pbK1, 32768 + 16384);
    mfmaq_f<0>(afr0, bfr0, &acc[0]);
    LBARR;
    rdA2(afr1, paK0, paK1, 32768 + 16384);
    mfmaq_f<1>(afr0, bfr1, &acc[0]);
    LBARR;
    if (more) { stA(1, 0, t3); stA(1, 1, t3); }
    mfmaq_f<0>(afr1, bfr0, &acc[4]);
    if (more) { VMW(4); } else { VMW(0); }
    LBARR;
    if (more) { rdA2(afr0, paK0, paK1, 0); rdB2(bfr0, pbK0, pbK1, 0); }
    if (more) { stB(1, 0, t3); stB(1, 1, t3); }
    mfmaq_f<1>(afr1, bfr1, &acc[4]);
  }

  // Epilogue. EPI7/8 accumulate per-row sum-of-squares into ssb.
#pragma unroll
  for (int f = 0; f < 8; ++f) {
    float ssp[4] = {0.0f, 0.0f, 0.0f, 0.0f};
#pragma unroll
    for (int g = 0; g < 4; ++g) {
      long col = n0 + wn * 64 + g * 16 + (lane & 15);
      float bv = (EPI == 6) ? 0.0f : biasp[col];
      if (EPI == 7 || EPI == 8) bv += aux[col];  // aux = bo
      float gv = (EPI == 5) ? aux[col] : 0.0f;   // aux = g1
#pragma unroll
      for (int r = 0; r < 4; ++r) {
        long row = m0 + wm * 128 + f * 16 + (lane >> 4) * 4 + r;
        float o = acc[f][g][r] + bv;
        if (EPI == 7) o += b2f(residb[row * (long)ldr + col]);
        if (EPI == 5) {
          float rsv = rsqrtf(ssb[row] * (1.0f / 1024.0f) + 1e-6f);
          o += b2f(residb[row * (long)ldr + col]) * rsv * gv;
        }
        if (EPI == 7 || EPI == 8) ssp[r] += o * o;
        C[row * (long)ldc + col] = f2b(o);
      }
    }
    if (EPI == 7 || EPI == 8) {
#pragma unroll
      for (int r = 0; r < 4; ++r) {
        float p = ssp[r];
        p += __shfl_xor(p, 1, 64);
        p += __shfl_xor(p, 2, 64);
        p += __shfl_xor(p, 4, 64);
        p += __shfl_xor(p, 8, 64);
        if ((lane & 15) == 0) {
          long row = m0 + wm * 128 + f * 16 + (lane >> 4) * 4 + r;
          atomicAdd(&ssb[row], p);
        }
      }
    }
  }
}

// ---------------------------------------------------------------------------
// m97-structure 128^2 GEMM (2 blocks/CU). EPI 4: tanh(rs(ssb[row])*acc+bias);
// EPI 5: no bias ; EPI 6: no bias + per-batch identity (+1 on (row&1023)==col).
// ---------------------------------------------------------------------------
template <int EPI>
__global__ __launch_bounds__(256, 2) void gemm_bt(
    const unsigned short* __restrict__ A, int lda,
    const unsigned short* __restrict__ Bt, int ldb,
    unsigned short* __restrict__ C, int ldc,
    const float* __restrict__ bias, const float* __restrict__ ssb, int K) {
  __shared__ __align__(16) unsigned short Asm[128 * 32];
  __shared__ __align__(16) unsigned short Bsm[128 * 32];
  const int tid = threadIdx.x;
  const int lane = tid & 63, wid = tid >> 6;
  const int wr = wid >> 1, wc = wid & 1;
  const long m0 = (long)blockIdx.y * 128;
  const long n0 = (long)blockIdx.x * 128;

  f32x4 acc[4][4] = {};

  for (int kk = 0; kk < K; kk += 32) {
    __syncthreads();
#pragma unroll
    for (int i = 0; i < 2; ++i) {
      int slot = i * 256 + tid;
      int r = slot >> 2, cg = (slot & 3) * 8;
      gload16(A + (m0 + r) * (long)lda + kk + cg, &Asm[slot * 8]);
      gload16(Bt + (n0 + r) * (long)ldb + kk + cg, &Bsm[slot * 8]);
    }
    __syncthreads();
    short8 af[4], bfr[4];
#pragma unroll
    for (int mt = 0; mt < 4; ++mt)
      af[mt] = *(const short8*)&Asm[(wr * 64 + mt * 16 + (lane & 15)) * 32 + (lane >> 4) * 8];
#pragma unroll
    for (int nt = 0; nt < 4; ++nt)
      bfr[nt] = *(const short8*)&Bsm[(wc * 64 + nt * 16 + (lane & 15)) * 32 + (lane >> 4) * 8];
#pragma unroll
    for (int mt = 0; mt < 4; ++mt)
#pragma unroll
      for (int nt = 0; nt < 4; ++nt)
        acc[mt][nt] = __builtin_amdgcn_mfma_f32_16x16x32_bf16(af[mt], bfr[nt], acc[mt][nt], 0, 0, 0);
  }

  const long row0 = m0 + wr * 64 + ((lane >> 4) * 4);
  const long col0 = n0 + wc * 64 + (lane & 15);
#pragma unroll
  for (int mt = 0; mt < 4; ++mt) {
#pragma unroll
    for (int nt = 0; nt < 4; ++nt) {
      long col = col0 + nt * 16;
      float bv = (EPI == 5 || EPI == 6) ? 0.0f : bias[col];
      f32x4 v = acc[mt][nt];
#pragma unroll
      for (int r = 0; r < 4; ++r) {
        long row = row0 + mt * 16 + r;
        float o = v[r];
        if (EPI == 4) {
          float rsv = rsqrtf(ssb[row] * (1.0f / 1024.0f) + 1e-6f);
          o = tanhf(o * rsv + bv);
        } else {
          o += bv;
          if (EPI == 6) o += ((row & 1023) == col) ? 1.0f : 0.0f;
        }
        C[row * (long)ldc + col] = f2b(o);
      }
    }
  }
}

// ---------------------------------------------------------------------------
// scores via MFMA (verified rounds 5-16); QK buffer stride 2048.
// ---------------------------------------------------------------------------
__device__ __forceinline__ int sperm(int e) { return ((e + (e >> 3)) & 7) << 4; }

__global__ __launch_bounds__(256) void scores_mfma(
    const unsigned short* __restrict__ QK, float* __restrict__ part) {
  __shared__ __align__(16) char lds[32768];
  int bh = blockIdx.x, seg = blockIdx.y;
  int b = bh >> 4, h = bh & 15;
  int tid = threadIdx.x, lane = tid & 63, wid = tid >> 6;
  int e0 = (tid & 7) * 8;
  int sl0 = (tid >> 3) * 4;
  const unsigned short* Qg = QK + h * 64;
  const unsigned short* Kg = QK + 1024 + h * 64;
  f32x4 acc[4] = {};

  for (int ch = 0; ch < 8; ++ch) {
    long S0 = (long)b * 4096 + seg * 1024 + ch * 128;
    __syncthreads();
    short8 kv0 = *(const short8*)(Kg + (S0 + sl0 + 0) * 2048 + e0);
    short8 kv1 = *(const short8*)(Kg + (S0 + sl0 + 1) * 2048 + e0);
    short8 kv2 = *(const short8*)(Kg + (S0 + sl0 + 2) * 2048 + e0);
    short8 kv3 = *(const short8*)(Kg + (S0 + sl0 + 3) * 2048 + e0);
    short8 qv0 = *(const short8*)(Qg + (S0 + sl0 + 0) * 2048 + e0);
    short8 qv1 = *(const short8*)(Qg + (S0 + sl0 + 1) * 2048 + e0);
    short8 qv2 = *(const short8*)(Qg + (S0 + sl0 + 2) * 2048 + e0);
    short8 qv3 = *(const short8*)(Qg + (S0 + sl0 + 3) * 2048 + e0);
#pragma unroll
    for (int je = 0; je < 8; ++je) {
      int e = e0 + je;
      int sw = sperm(e);
      char* rowK = lds + e * 256;
      char* rowQ = lds + 16384 + e * 256;
      unsigned int klo = (unsigned short)kv0[je] | ((unsigned int)(unsigned short)kv1[je] << 16);
      unsigned int khi = (unsigned short)kv2[je] | ((unsigned int)(unsigned short)kv3[je] << 16);
      unsigned int qlo = (unsigned short)qv0[je] | ((unsigned int)(unsigned short)qv1[je] << 16);
      unsigned int qhi = (unsigned short)qv2[je] | ((unsigned int)(unsigned short)qv3[je] << 16);
      *(unsigned int*)(rowK + ((sl0 * 2) ^ sw)) = klo;
      *(unsigned int*)(rowK + ((sl0 * 2 + 4) ^ sw)) = khi;
      *(unsigned int*)(rowQ + ((sl0 * 2) ^ sw)) = qlo;
      *(unsigned int*)(rowQ + ((sl0 * 2 + 4) ^ sw)) = qhi;
    }
    __syncthreads();
#pragma unroll
    for (int ksi = 0; ksi < 4; ++ksi) {
      int colb = ksi * 64 + (lane >> 4) * 16;
      int erA = wid * 16 + (lane & 15);
      short8 af = *(const short8*)(lds + erA * 256 + (colb ^ sperm(erA)));
#pragma unroll
      for (int n = 0; n < 4; ++n) {
        int erB = n * 16 + (lane & 15);
        short8 bf = *(const short8*)(lds + 16384 + erB * 256 + (colb ^ sperm(erB)));
        acc[n] = __builtin_amdgcn_mfma_f32_16x16x32_bf16(af, bf, acc[n], 0, 0, 0);
      }
    }
  }
  float* dst = part + ((long)bh * 4 + seg) * 4096;
#pragma unroll
  for (int n = 0; n < 4; ++n)
#pragma unroll
    for (int r = 0; r < 4; ++r) {
      int k = wid * 16 + (lane >> 4) * 4 + r;
      int q = n * 16 + (lane & 15);
      dst[k * 64 + q] = acc[n][r];
    }
}

// softmax over k (per q column), scores/8; writes w row-major: Wb[bh][k][q]
__global__ __launch_bounds__(64) void softmax_Wb(
    const float* __restrict__ part, const int* __restrict__ mask,
    unsigned short* __restrict__ Wb) {
  __shared__ float lt[64][65];
  int bh = blockIdx.x, q = threadIdx.x;
  int b = bh >> 4;
  const float* p0 = part + (long)bh * 4 * 4096;
  float s[64];
#pragma unroll
  for (int k = 0; k < 64; ++k)
    s[k] = p0[k * 64 + q] + p0[4096 + k * 64 + q] + p0[8192 + k * 64 + q] + p0[12288 + k * 64 + q];
  bool live = (mask[b * 64 + q] != 0);
  float m = -1e30f;
#pragma unroll
  for (int k = 0; k < 64; ++k) m = fmaxf(m, s[k]);
  float sum = 0.0f;
#pragma unroll
  for (int k = 0; k < 64; ++k) {
    s[k] = __expf((s[k] - m) * 0.125f);
    sum += s[k];
  }
  float inv = live ? 1.0f / sum : 0.0f;
#pragma unroll
  for (int k = 0; k < 64; ++k) lt[k][q] = s[k] * inv;
  __syncthreads();
  unsigned short* o = Wb + (long)bh * 4096 + q * 64;
#pragma unroll
  for (int j8 = 0; j8 < 8; ++j8) {
    short8 ov;
#pragma unroll
    for (int j = 0; j < 8; ++j) ov[j] = (short)f2b(lt[q][j8 * 8 + j]);
    *(short8*)(o + j8 * 8) = ov;
  }
}

// WPT[b][d][h*64+k] = sum_q Wo[h*64+q][d] * w_bh[k][q]
// Fused: atomicAdd partial of hb[b][d] = sum_col WPT[d][col]*bv[col].
__global__ __launch_bounds__(256) void wpt_kernel(
    const unsigned short* __restrict__ WoT, const unsigned short* __restrict__ Wb,
    unsigned short* __restrict__ WPT, const float* __restrict__ bv,
    float* __restrict__ hb) {
  int dblk = blockIdx.x;   // 4
  int h = blockIdx.y;      // 16
  int b = blockIdx.z;      // 8
  int tid = threadIdx.x, lane = tid & 63, wid = tid >> 6;
  int d0 = dblk * 256 + wid * 64;
  const unsigned short* wb = Wb + (long)(b * 16 + h) * 4096;
  f32x4 acc[4][4] = {};
#pragma unroll
  for (int ks = 0; ks < 2; ++ks) {
    short8 bf[4];
#pragma unroll
    for (int nt = 0; nt < 4; ++nt)
      bf[nt] = *(const short8*)(wb + (nt * 16 + (lane & 15)) * 64 + ks * 32 + (lane >> 4) * 8);
#pragma unroll
    for (int mt = 0; mt < 4; ++mt) {
      short8 af = *(const short8*)(WoT + (long)(d0 + mt * 16 + (lane & 15)) * 1024 + h * 64 + ks * 32 + (lane >> 4) * 8);
#pragma unroll
      for (int nt = 0; nt < 4; ++nt)
        acc[mt][nt] = __builtin_amdgcn_mfma_f32_16x16x32_bf16(af, bf[nt], acc[mt][nt], 0, 0, 0);
    }
  }
  float bvv[4];
#pragma unroll
  for (int nt = 0; nt < 4; ++nt) bvv[nt] = bv[h * 64 + nt * 16 + (lane & 15)];
#pragma unroll
  for (int mt = 0; mt < 4; ++mt) {
#pragma unroll
    for (int r = 0; r < 4; ++r) {
      long row = d0 + mt * 16 + (lane >> 4) * 4 + r;
      float p = 0.0f;
#pragma unroll
      for (int nt = 0; nt < 4; ++nt) {
        float o = acc[mt][nt][r];
        WPT[(long)b * 1048576 + row * 1024 + h * 64 + nt * 16 + (lane & 15)] = f2b(o);
        p += o * bvv[nt];
      }
      p += __shfl_xor(p, 1, 64);
      p += __shfl_xor(p, 2, 64);
      p += __shfl_xor(p, 4, 64);
      p += __shfl_xor(p, 8, 64);
      if ((lane & 15) == 0) atomicAdd(&hb[b * 1024 + row], p);
    }
  }
}

// rmsnorm over D=1024; one block per row. bf16 in; f32 out.
__global__ __launch_bounds__(256) void rmsnorm_k(
    const unsigned short* __restrict__ in, const float* __restrict__ g,
    float* __restrict__ outf) {
  long row = blockIdx.x;
  int tid = threadIdx.x;
  short4v u = *(const short4v*)(in + row * 1024 + tid * 4);
  float v[4];
  float ss = 0.0f;
#pragma unroll
  for (int i = 0; i < 4; ++i) {
    v[i] = b2f((unsigned short)u[i]);
    ss += v[i] * v[i];
  }
#pragma unroll
  for (int off = 32; off > 0; off >>= 1) ss += __shfl_xor(ss, off, 64);
  __shared__ float wsum[4];
  if ((tid & 63) == 0) wsum[tid >> 6] = ss;
  __syncthreads();
  float tot = wsum[0] + wsum[1] + wsum[2] + wsum[3];
  float rsv = rsqrtf(tot * (1.0f / 1024.0f) + 1e-6f);
  f32x4 gv = *(const f32x4*)(g + tid * 4);
  f32x4 ov;
#pragma unroll
  for (int i = 0; i < 4; ++i) ov[i] = v[i] * rsv * gv[i];
  *(f32x4*)(outf + row * 1024 + tid * 4) = ov;
}

// ---------------------------------------------------------------------------
extern "C" void kernel_launch(void* const* d_in, const int* in_sizes, int n_in,
                              void* d_out, int out_size, void* d_ws, size_t ws_size,
                              hipStream_t stream) {
  const float* x  = (const float*)d_in[0];
  const int* mask = (const int*)d_in[1];
  const float* Wq = (const float*)d_in[2];
  const float* bq = (const float*)d_in[3];
  const float* Wk = (const float*)d_in[4];
  const float* bk = (const float*)d_in[5];
  const float* Wv = (const float*)d_in[6];
  const float* bv = (const float*)d_in[7];
  const float* Wo = (const float*)d_in[8];
  const float* bo = (const float*)d_in[9];
  const float* W1 = (const float*)d_in[10];
  const float* b1 = (const float*)d_in[11];
  const float* W2 = (const float*)d_in[12];
  const float* b2 = (const float*)d_in[13];
  const float* g1 = (const float*)d_in[14];
  const float* g2 = (const float*)d_in[15];

  char* ws = (char*)d_ws;
  size_t off = 0;
  auto alc = [&](size_t n) { size_t o = off; off += (n + 255) & ~(size_t)255; return o; };
  unsigned short* BqkT  = (unsigned short*)(ws + alc(2048UL * 1024 * 2));
  unsigned short* WoT   = (unsigned short*)(ws + alc(1024UL * 1024 * 2));
  unsigned short* W1T   = (unsigned short*)(ws + alc(128UL * 1024 * 2));    // g1-folded
  unsigned short* W2T   = (unsigned short*)(ws + alc(1024UL * 128 * 2));
  unsigned short* WvR   = (unsigned short*)(ws + alc(1024UL * 1024 * 2));
  float*          bqkv  = (float*)(ws + alc(3072UL * 4));
  float*          HBb   = (float*)(ws + alc(8192UL * 4));
  unsigned short* R0    = (unsigned short*)(ws + alc(32768UL * 1024 * 2));  // xb -> hf
  unsigned short* R1    = (unsigned short*)(ws + alc(32768UL * 2048 * 2));  // QK
  unsigned short* R2    = (unsigned short*)(ws + alc(32768UL * 1024 * 2));  // h1
  unsigned short* WPb   = (unsigned short*)(ws + alc(8UL * 1048576 * 2));   // WPT
  unsigned short* WVPb  = (unsigned short*)(ws + alc(8UL * 1048576 * 2));   // WVP (+I)
  unsigned short* Tb    = (unsigned short*)(ws + alc(32768UL * 128 * 2));
  float*          SP    = (float*)(ws + alc(512UL * 4096 * 4));
  unsigned short* Wbuf  = (unsigned short*)(ws + alc(128UL * 4096 * 2));
  float*          SSb   = (float*)(ws + alc(32768UL * 4));
  if (ws_size < off) return;

  // Dataflow (C always disjoint from A/B/resid):
  //   prep:   x -> xb(R0); weights; bqkv; zero HBb/SSb
  //   QK:     xb(R0) @ BqkT -> QK(R1)                 [gemm8p EPI0]
  //   scores: QK(R1) -> SP ; softmax -> Wbuf
  //   wpt:    -> WPT(WPb) + atomics hb(HBb)
  //   WVP+I:  WPT @ WvR (+diag 1) -> WVP(WVPb)        [gemm_bt EPI6, full GPU]
  //   h1:     xb @ (WVP_b)^T + hb_b + bo -> h1(R2)    [gemm8p EPI8; SS -> SSb]
  //   FF1:    h1 @ W1g, tanh(rs(SSb)*acc+b1) -> t(Tb) [gemm_bt EPI4]
  //   FF2:    t @ W2T + b2 + h1*rs(SSb)*g1 -> hf(R0)  [gemm8p EPI5; xb dead]
  //   rms2:   hf(R0) -> out
  unsigned short* xb   = R0;
  unsigned short* HFb  = R0;
  unsigned short* QKb  = R1;
  unsigned short* H1b  = R2;
  float* outp = (float*)d_out;

  prep_kernel<<<17475, 256, 0, stream>>>(x, xb, Wq, Wk, Wv, Wo, W1, W2, bq, bk, bv, g1,
                                         BqkT, WoT, W1T, W2T, WvR, bqkv, HBb, SSb);
  // QK = xb @ [Wq|Wk]^T + b  (N=2048; grid 128x8 = 1024)
  gemm8p<0, 0, 0><<<1024, 512, 131072, stream>>>(xb, 1024, BqkT, 1024, QKb, 2048,
                                                 bqkv, nullptr, 0, nullptr, nullptr,
                                                 1024, 8);
  scores_mfma<<<dim3(128, 4), 256, 0, stream>>>(QKb, SP);
  softmax_Wb<<<128, 64, 0, stream>>>(SP, mask, Wbuf);
  wpt_kernel<<<dim3(4, 16, 8), 256, 0, stream>>>(WoT, Wbuf, WPb, bqkv + 2048, HBb);
  // WVP = WPT_stacked @ WvR^T + I_b  (M=8192; grid (8,64)=512, 2/CU)
  gemm_bt<6><<<dim3(8, 64), 256, 0, stream>>>(WPb, 1024, WvR, 1024, WVPb, 1024,
                                              nullptr, nullptr, 1024);
  // h1 = xb @ (WVP_b)^T + hb_b + bo ; SS atomics into SSb (resid folded in B)
  gemm8p<8, 1, 1><<<512, 512, 131072, stream>>>(xb, 1024, WVPb, 1024, H1b, 1024,
                                                HBb, nullptr, 0, SSb, bo,
                                                1024, 4);
  // t = tanh(rs * (h1 @ W1g^T) + b1)
  gemm_bt<4><<<dim3(1, 256), 256, 0, stream>>>(H1b, 1024, W1T, 1024, Tb, 128, b1, SSb, 1024);
  // hf = t@W2T + b2 + h1*rs*g1
  gemm8p<5, 0, 0><<<512, 512, 131072, stream>>>(Tb, 128, W2T, 128, HFb, 1024,
                                                b2, H1b, 1024, SSb, g1,
                                                128, 4);
  rmsnorm_k<<<32768, 256, 0, stream>>>(HFb, g2, outp);
}